// Round 1
// baseline (4093.459 us; speedup 1.0000x reference)
//
#include <hip/hip_runtime.h>
#include <math.h>

#define DEV __device__ __forceinline__

// ---------------- helpers ----------------
DEV float blk_sum(float v, float* sb) {
  #pragma unroll
  for (int o = 32; o > 0; o >>= 1) v += __shfl_down(v, o, 64);
  int lane = threadIdx.x & 63, wid = threadIdx.x >> 6;
  __syncthreads();
  if (lane == 0) sb[wid] = v;
  __syncthreads();
  return sb[0] + sb[1] + sb[2] + sb[3];
}

DEV float silu_f(float x) { return x / (1.f + expf(-x)); }

DEV int imin_i(int a, int b) { return a < b ? a : b; }
DEV int imax_i(int a, int b) { return a > b ? a : b; }

#define BN_SCALE 0.9999950000374997f /* 1/sqrt(1+1e-5) */

// ---------------- stage 1: pyramid ----------------

// copy x (B,512,256) into xcT channels 512..1023  (xcT layout: (b, l, c=1024))
__global__ __launch_bounds__(256) void copyx_kernel(const float* __restrict__ x,
                                                    float* __restrict__ xcT) {
  int idx = blockIdx.x * 256 + threadIdx.x;      // 8*512*256
  int l = idx & 255; int bc = idx >> 8; int c = bc & 511; int b = bc >> 9;
  xcT[((long)b * 256 + l) * 1024 + 512 + c] = x[idx];
}

// pool0: cbr at full res then mean over pixels; broadcast into xcT[:, :, o]
__global__ __launch_bounds__(256) void pool0_kernel(const float* __restrict__ x,
    const float* __restrict__ pw, const float* __restrict__ bng,
    const float* __restrict__ bnb, float* __restrict__ xcT) {
  __shared__ float sb[8];
  int b = blockIdx.x, o = blockIdx.y, p = threadIdx.x;
  const float* xp = x + (long)b * 512 * 256 + p;
  const float* w = pw + (long)o * 512;
  float s = 0.f;
  for (int c = 0; c < 512; c++) s = fmaf(xp[(long)c * 256], w[c], s);
  float gs = bng[o] * BN_SCALE;
  float v = fminf(fmaxf(fmaf(s, gs, bnb[o]), 0.f), 6.f);
  float m = blk_sum(v, sb) * (1.f / 256.f);
  xcT[((long)b * 256 + p) * 1024 + o] = m;
}

// adaptive average pool x (16x16) -> (s x s)
__global__ void apool_kernel(const float* __restrict__ x, float* __restrict__ pooled, int s) {
  int s2 = s * s;
  int idx = blockIdx.x * 256 + threadIdx.x;
  if (idx >= 8 * 512 * s2) return;
  int op = idx % s2; int bc = idx / s2;
  int oh = op / s, ow = op % s;
  int h0 = oh * 16 / s, h1 = (oh * 16 + 16 + s - 1) / s;
  int w0 = ow * 16 / s, w1 = (ow * 16 + 16 + s - 1) / s;
  const float* xp = x + (long)bc * 256;
  float sum = 0.f;
  for (int h = h0; h < h1; h++)
    for (int w = w0; w < w1; w++) sum += xp[h * 16 + w];
  pooled[(long)bc * s2 + op] = sum / (float)((h1 - h0) * (w1 - w0));
}

// 1x1 conv + bn + relu6 on pooled
__global__ void cbr_kernel(const float* __restrict__ pooled, const float* __restrict__ pw_i,
    const float* __restrict__ bng_i, const float* __restrict__ bnb_i,
    float* __restrict__ ys, int s2) {
  int b = blockIdx.x, o = blockIdx.y, p = threadIdx.x;
  if (p >= s2) return;
  const float* pp = pooled + (long)b * 512 * s2 + p;
  const float* w = pw_i + (long)o * 512;
  float sum = 0.f;
  for (int c = 0; c < 512; c++) sum = fmaf(pp[(long)c * s2], w[c], sum);
  float gs = bng_i[o] * BN_SCALE;
  ys[((long)b * 128 + o) * s2 + p] = fminf(fmaxf(fmaf(sum, gs, bnb_i[o]), 0.f), 6.f);
}

// jax.image.resize bilinear (half-pixel, edge-normalized == clamp) s x s -> 16 x 16
__global__ void resize_kernel(const float* __restrict__ ys, float* __restrict__ xcT,
                              int s, int ch0) {
  int b = blockIdx.x, o = blockIdx.y, t = threadIdx.x;
  int h = t >> 4, w = t & 15;
  float scale = (float)s / 16.f;
  float sh = (h + 0.5f) * scale - 0.5f;
  float sw = (w + 0.5f) * scale - 0.5f;
  int h0 = (int)floorf(sh); float fh = sh - (float)h0;
  int w0 = (int)floorf(sw); float fw = sw - (float)w0;
  int ha = imin_i(imax_i(h0, 0), s - 1), hb = imin_i(imax_i(h0 + 1, 0), s - 1);
  int wa = imin_i(imax_i(w0, 0), s - 1), wb = imin_i(imax_i(w0 + 1, 0), s - 1);
  const float* yp = ys + ((long)b * 128 + o) * s * s;
  float v = (1.f - fh) * ((1.f - fw) * yp[ha * s + wa] + fw * yp[ha * s + wb]) +
            fh * ((1.f - fw) * yp[hb * s + wa] + fw * yp[hb * s + wb]);
  xcT[((long)b * 256 + t) * 1024 + ch0 + o] = v;
}

// channel means over L
__global__ __launch_bounds__(256) void xcmean_kernel(const float* __restrict__ xcT,
                                                     float* __restrict__ xm) {
  int idx = blockIdx.x * 256 + threadIdx.x;   // 8192
  int c = idx & 1023; int b = idx >> 10;
  const float* p = xcT + (long)b * 256 * 1024 + c;
  float s = 0.f;
  for (int l = 0; l < 256; l++) s += p[(long)l * 1024];
  xm[idx] = s * (1.f / 256.f);
}

// logits -> softmax -> top4 scatter
__global__ void gate_kernel(const float* __restrict__ xm, const float* __restrict__ gww,
                            float* __restrict__ gwout) {
  __shared__ float lg[64];
  int t = threadIdx.x;          // 64 threads
  int b = t >> 3, j = t & 7;
  const float* xb = xm + b * 1024;
  const float* wj = gww + j * 1024;
  float s = 0.f;
  for (int c = 0; c < 1024; c++) s = fmaf(xb[c], wj[c], s);
  lg[t] = s;
  __syncthreads();
  if (t < 8) {
    float v[8], mx = -1e30f;
    for (int i = 0; i < 8; i++) { v[i] = lg[t * 8 + i]; mx = fmaxf(mx, v[i]); }
    float den = 0.f;
    for (int i = 0; i < 8; i++) { v[i] = expf(v[i] - mx); den += v[i]; }
    float inv = 1.f / den;
    float sc[8], out[8], tmp[8];
    for (int i = 0; i < 8; i++) { sc[i] = v[i] * inv; out[i] = 0.f; tmp[i] = sc[i]; }
    for (int it = 0; it < 4; it++) {
      int bi = 0; float bv = tmp[0];
      for (int i = 1; i < 8; i++) if (tmp[i] > bv) { bv = tmp[i]; bi = i; }
      out[bi] = bv; tmp[bi] = -1e30f;
    }
    for (int i = 0; i < 8; i++) gwout[t * 8 + i] = out[i];
  }
}

// ---------------- stage 2: cross-scan + fd_gate ----------------

DEV int scan_src(int k, int l) {
  switch (k) {
    case 0: return l;
    case 1: return ((l & 15) << 4) | (l >> 4);
    case 2: return 255 - l;
    case 3: { int l2 = 255 - l; return ((l2 & 15) << 4) | (l2 >> 4); }
    case 4: { int h = l & 15, w = l >> 4; return (h << 4) | ((h + w) & 15); }
    case 5: { int h = l & 15, w = l >> 4; return (h << 4) | ((w - h) & 15); }
    case 6: { int l2 = 255 - l; int h = l2 & 15, w = l2 >> 4; return (h << 4) | ((h + w) & 15); }
    default:{ int l2 = 255 - l; int h = l2 & 15, w = l2 >> 4; return (h << 4) | ((w - h) & 15); }
  }
}

__global__ __launch_bounds__(256) void fd_gate_kernel(const float* __restrict__ xcT,
    const float* __restrict__ lng, const float* __restrict__ lnb,
    const float* __restrict__ fsc, float* __restrict__ xg, int k0) {
  __shared__ float sb[8];
  int l = blockIdx.x;
  int rg = blockIdx.y;                 // kk*8 + b
  int kk = rg >> 3, b = rg & 7;
  int k = k0 + kk;
  int t = threadIdx.x;
  int p = scan_src(k, l);
  float4 cv = *((const float4*)(xcT + ((long)b * 256 + p) * 1024) + t);
  float4 pv = make_float4(0.f, 0.f, 0.f, 0.f);
  if (l > 0) {
    int pm = scan_src(k, l - 1);
    pv = *((const float4*)(xcT + ((long)b * 256 + pm) * 1024) + t);
  }
  float d0 = cv.x - pv.x, d1 = cv.y - pv.y, d2 = cv.z - pv.z, d3 = cv.w - pv.w;
  float mu = blk_sum(d0 + d1 + d2 + d3, sb) * (1.f / 1024.f);
  float e0 = d0 - mu, e1 = d1 - mu, e2 = d2 - mu, e3 = d3 - mu;
  float var = blk_sum(e0*e0 + e1*e1 + e2*e2 + e3*e3, sb) * (1.f / 1024.f);
  float rstd = rsqrtf(var + 1e-5f);
  float4 g4 = *((const float4*)lng + t);
  float4 b4 = *((const float4*)lnb + t);
  float n0 = fmaf(e0 * rstd, g4.x, b4.x);
  float n1 = fmaf(e1 * rstd, g4.y, b4.y);
  float n2 = fmaf(e2 * rstd, g4.z, b4.z);
  float n3 = fmaf(e3 * rstd, g4.w, b4.w);
  float ss = blk_sum(n0*n0 + n1*n1 + n2*n2 + n3*n3, sb);
  float nd = sqrtf(ss) * fsc[0];
  float gate = 0.2f + 0.8f * tanhf(fabsf(nd));
  float4 o;
  o.x = cv.x * gate; o.y = cv.y * gate; o.z = cv.z * gate; o.w = cv.w * gate;
  *((float4*)(xg + ((long)rg * 256 + l) * 1024) + t) = o;
}

// ---------------- fp32 tiled GEMM: C[M,N] = A[M,K] * B[N,K]^T ----------------
// 128x64 block tile, 256 threads, 8x4 micro-tile, K-step 16.  EPI=1: softplus(x+bias[n])
template<int EPI>
__global__ __launch_bounds__(256) void gemm_nt(
    const float* __restrict__ A, long lda, long aK,
    const float* __restrict__ Bw, long bK,
    float* __restrict__ C, long ldc, long cK,
    int N, int Kd,
    const float* __restrict__ bias, long biasK) {
  __shared__ float As[16][132];
  __shared__ float Bs[16][68];
  const int t = threadIdx.x;
  const int kk = blockIdx.z;
  A += (long)kk * aK; Bw += (long)kk * bK; C += (long)kk * cK;
  if (EPI == 1) bias += (long)kk * biasK;
  const int m_blk = blockIdx.x * 128;
  const int n_blk = blockIdx.y * 64;
  const int tx = t & 15, ty = t >> 4;
  const int aq = t & 3, ar = t >> 2;   // ar: 0..63
  float acc[8][4];
  #pragma unroll
  for (int i = 0; i < 8; i++)
    #pragma unroll
    for (int j = 0; j < 4; j++) acc[i][j] = 0.f;

  for (int kt = 0; kt < Kd; kt += 16) {
    float4 a0 = *(const float4*)(A + (long)(m_blk + ar) * lda + kt + aq * 4);
    float4 a1 = *(const float4*)(A + (long)(m_blk + 64 + ar) * lda + kt + aq * 4);
    float4 b0 = make_float4(0.f, 0.f, 0.f, 0.f);
    int bn = n_blk + ar;
    if (bn < N) b0 = *(const float4*)(Bw + (long)bn * Kd + kt + aq * 4);
    __syncthreads();
    As[aq*4+0][ar] = a0.x; As[aq*4+1][ar] = a0.y; As[aq*4+2][ar] = a0.z; As[aq*4+3][ar] = a0.w;
    As[aq*4+0][64+ar] = a1.x; As[aq*4+1][64+ar] = a1.y; As[aq*4+2][64+ar] = a1.z; As[aq*4+3][64+ar] = a1.w;
    Bs[aq*4+0][ar] = b0.x; Bs[aq*4+1][ar] = b0.y; Bs[aq*4+2][ar] = b0.z; Bs[aq*4+3][ar] = b0.w;
    __syncthreads();
    #pragma unroll
    for (int k2 = 0; k2 < 16; k2++) {
      float av[8], bv[4];
      #pragma unroll
      for (int i = 0; i < 8; i++) av[i] = As[k2][ty * 8 + i];
      #pragma unroll
      for (int j = 0; j < 4; j++) bv[j] = Bs[k2][tx * 4 + j];
      #pragma unroll
      for (int i = 0; i < 8; i++)
        #pragma unroll
        for (int j = 0; j < 4; j++) acc[i][j] = fmaf(av[i], bv[j], acc[i][j]);
    }
  }
  #pragma unroll
  for (int i = 0; i < 8; i++) {
    long m = m_blk + ty * 8 + i;
    #pragma unroll
    for (int j = 0; j < 4; j++) {
      int n = n_blk + tx * 4 + j;
      if (n < N) {
        float v = acc[i][j];
        if (EPI == 1) {
          v += bias[n];
          v = log1pf(expf(-fabsf(v))) + fmaxf(v, 0.f);   // softplus
        }
        C[m * ldc + n] = v;
      }
    }
  }
}

// ---------------- causal depthwise conv (kernel 4) + silu, in place ----------------
__global__ __launch_bounds__(256) void conv_silu_kernel(float* u,
    const float* __restrict__ cw, const float* __restrict__ cb, int k0) {
  long tid = (long)blockIdx.x * 256 + threadIdx.x;  // NK*8*2048
  int d = (int)(tid & 2047);
  long rg = tid >> 11;                               // kk*8 + b
  int k = k0 + (int)(rg >> 3);
  const float* w = cw + ((long)k * 2048 + d) * 4;
  float w0 = w[0], w1 = w[1], w2 = w[2], w3 = w[3];
  float bias = cb[(long)k * 2048 + d];
  float* base = u + rg * 256 * 2048 + d;
  float x0 = 0.f, x1 = 0.f, x2 = 0.f;
  #pragma unroll 4
  for (int l = 0; l < 256; l++) {
    float x3 = base[(long)l * 2048];
    float v = bias + w0 * x0 + w1 * x1 + w2 * x2 + w3 * x3;
    base[(long)l * 2048] = silu_f(v);
    x0 = x1; x1 = x2; x2 = x3;
  }
}

// ---------------- selective scan + fused epilogue ----------------
// one thread per (kk,b,d); h[16] in regs; B/C staged in LDS 8 steps per barrier.
// writes (y + u*Dp)*silu(z) in place over dt buffer.
__global__ __launch_bounds__(256) void scan_kernel(
    float* dtio, const float* __restrict__ u, const float* __restrict__ z,
    const float* __restrict__ xdbl, const float* __restrict__ A_log,
    const float* __restrict__ Dp, int k0) {
  int t = threadIdx.x;
  int d = blockIdx.x * 256 + t;
  int rg = blockIdx.y;                 // kk*8 + b
  int k = k0 + (rg >> 3);
  float Av[16];
  const float* Ap = A_log + ((long)k * 2048 + d) * 16;
  #pragma unroll
  for (int s = 0; s < 16; s++) Av[s] = -expf(Ap[s]);
  float dp = Dp[(long)k * 2048 + d];
  __shared__ float BC[8][32];
  float h[16];
  #pragma unroll
  for (int s = 0; s < 16; s++) h[s] = 0.f;
  long rbase = (long)rg * 256;
  for (int l8 = 0; l8 < 256; l8 += 8) {
    __syncthreads();
    BC[t >> 5][t & 31] = xdbl[(rbase + l8 + (t >> 5)) * 96 + 64 + (t & 31)];
    __syncthreads();
    #pragma unroll
    for (int j = 0; j < 8; j++) {
      long r = rbase + l8 + j;
      float dtv = dtio[r * 2048 + d];
      float uv = u[r * 2048 + d];
      float zv = z[r * 2048 + d];
      float dtu = dtv * uv;
      float y = 0.f;
      #pragma unroll
      for (int s = 0; s < 16; s++) {
        float dA = expf(dtv * Av[s]);
        h[s] = fmaf(dA, h[s], dtu * BC[j][s]);
        y = fmaf(h[s], BC[j][16 + s], y);
      }
      dtio[r * 2048 + d] = (y + uv * dp) * silu_f(zv);
    }
  }
}

// ---------------- cross merge (accumulating per direction group) ----------------
__global__ __launch_bounds__(256) void merge_kernel(const float* __restrict__ yo,
    const float* __restrict__ gw, float* __restrict__ out, int k0, int NK) {
  int b = blockIdx.x; int c0 = blockIdx.y * 4; int t = threadIdx.x;
  int h = t >> 4, w = t & 15;
  int l0 = t;
  int l1 = (w << 4) | h;
  int l4 = (((w - h) & 15) << 4) | h;
  int l5 = (((w + h) & 15) << 4) | h;
  int lk[8] = { l0, l1, 255 - l0, 255 - l1, l4, l5, 255 - l4, 255 - l5 };
  float a0 = 0.f, a1 = 0.f, a2 = 0.f, a3 = 0.f;
  for (int kk = 0; kk < NK; kk++) {
    int k = k0 + kk;
    float g = gw[b * 8 + k];
    const float4 p = *(const float4*)(yo + (((long)kk * 8 + b) * 256 + lk[k]) * 1024 + c0);
    a0 = fmaf(g, p.x, a0); a1 = fmaf(g, p.y, a1); a2 = fmaf(g, p.z, a2); a3 = fmaf(g, p.w, a3);
  }
  float* op = out + ((long)b * 1024 + c0) * 256 + t;
  if (k0 == 0) { op[0] = a0; op[256] = a1; op[512] = a2; op[768] = a3; }
  else         { op[0] += a0; op[256] += a1; op[512] += a2; op[768] += a3; }
}

// ---------------- host ----------------
extern "C" void kernel_launch(void* const* d_in, const int* in_sizes, int n_in,
                              void* d_out, int out_size, void* d_ws, size_t ws_size,
                              hipStream_t stream) {
  (void)in_sizes; (void)n_in; (void)out_size;
  const float* x      = (const float*)d_in[0];
  const float* pw     = (const float*)d_in[1];
  const float* bn_g   = (const float*)d_in[2];
  const float* bn_b   = (const float*)d_in[3];
  const float* gate_w = (const float*)d_in[4];
  const float* ln_g   = (const float*)d_in[5];
  const float* ln_b   = (const float*)d_in[6];
  const float* fd_s   = (const float*)d_in[7];
  const float* in_w   = (const float*)d_in[8];
  const float* cw     = (const float*)d_in[9];
  const float* cb     = (const float*)d_in[10];
  const float* xp_w   = (const float*)d_in[11];
  const float* dtp_w  = (const float*)d_in[12];
  const float* dtp_b  = (const float*)d_in[13];
  const float* A_log  = (const float*)d_in[14];
  const float* D_p    = (const float*)d_in[15];
  const float* out_w  = (const float*)d_in[16];
  float* out = (float*)d_out;
  float* ws = (float*)d_ws;

  size_t off = 0;
  auto alloc = [&](size_t n) { float* p = ws + off; off += n; return p; };
  float* xcT    = alloc(2097152);        // (b, l, 1024)
  float* pooled = alloc((size_t)8 * 512 * 169);
  float* ysb    = alloc((size_t)8 * 128 * 169);
  float* xm     = alloc(8192);
  float* gwb    = alloc(64);
  const size_t fixed = off;
  const size_t PK_XG = 2097152, PK_U = 4194304, PK_Z = 4194304,
               PK_DT = 4194304, PK_XD = 196608, PK_YO = 2097152;
  const size_t perk = PK_XG + PK_U + PK_Z + PK_DT + PK_XD + PK_YO;
  const size_t avail = ws_size / sizeof(float);
  int NK = 8;
  while (NK > 1 && fixed + perk * (size_t)NK > avail) NK >>= 1;
  float* xg  = alloc(PK_XG * NK);
  float* ub  = alloc(PK_U * NK);
  float* zb  = alloc(PK_Z * NK);
  float* dtb = alloc(PK_DT * NK);
  float* xdb = alloc(PK_XD * NK);
  float* yob = alloc(PK_YO * NK);

  // stage 1: pyramid + concat
  copyx_kernel<<<4096, 256, 0, stream>>>(x, xcT);
  pool0_kernel<<<dim3(8, 128), 256, 0, stream>>>(x, pw, bn_g, bn_b, xcT);
  const int svals[3] = {5, 9, 13};
  for (int i = 0; i < 3; i++) {
    int s = svals[i], s2 = s * s;
    int tot = 8 * 512 * s2;
    apool_kernel<<<(tot + 255) / 256, 256, 0, stream>>>(x, pooled, s);
    cbr_kernel<<<dim3(8, 128), 256, 0, stream>>>(pooled, pw + (long)(i + 1) * 128 * 512,
                                                 bn_g + (i + 1) * 128, bn_b + (i + 1) * 128,
                                                 ysb, s2);
    resize_kernel<<<dim3(8, 128), 256, 0, stream>>>(ysb, xcT, s, 128 * (i + 1));
  }
  xcmean_kernel<<<32, 256, 0, stream>>>(xcT, xm);
  gate_kernel<<<1, 64, 0, stream>>>(xm, gate_w, gwb);

  // stage 2: per-direction groups
  for (int k0 = 0; k0 < 8; k0 += NK) {
    fd_gate_kernel<<<dim3(256, NK * 8), 256, 0, stream>>>(xcT, ln_g, ln_b, fd_s, xg, k0);
    // u = xg @ in_w[k][0:2048].T
    gemm_nt<0><<<dim3(16, 32, NK), 256, 0, stream>>>(
        xg, 1024, (long)PK_XG, in_w + (long)k0 * 4096 * 1024, (long)4096 * 1024,
        ub, 2048, (long)PK_U, 2048, 1024, nullptr, 0);
    // z = xg @ in_w[k][2048:4096].T
    gemm_nt<0><<<dim3(16, 32, NK), 256, 0, stream>>>(
        xg, 1024, (long)PK_XG, in_w + (long)k0 * 4096 * 1024 + (long)2048 * 1024,
        (long)4096 * 1024, zb, 2048, (long)PK_Z, 2048, 1024, nullptr, 0);
    conv_silu_kernel<<<NK * 64, 256, 0, stream>>>(ub, cw, cb, k0);
    // x_dbl = u @ xp_w[k].T  (N=96)
    gemm_nt<0><<<dim3(16, 2, NK), 256, 0, stream>>>(
        ub, 2048, (long)PK_U, xp_w + (long)k0 * 96 * 2048, (long)96 * 2048,
        xdb, 96, (long)PK_XD, 96, 2048, nullptr, 0);
    // dt = softplus(x_dbl[:, :64] @ dtp_w[k].T + dtp_b[k])
    gemm_nt<1><<<dim3(16, 32, NK), 256, 0, stream>>>(
        xdb, 96, (long)PK_XD, dtp_w + (long)k0 * 2048 * 64, (long)2048 * 64,
        dtb, 2048, (long)PK_DT, 2048, 64, dtp_b + (long)k0 * 2048, 2048);
    // selective scan + (y + u*Dp)*silu(z), in place over dtb
    scan_kernel<<<dim3(8, NK * 8), 256, 0, stream>>>(dtb, ub, zb, xdb, A_log, D_p, k0);
    // y_out = y_full @ out_w[k].T
    gemm_nt<0><<<dim3(16, 16, NK), 256, 0, stream>>>(
        dtb, 2048, (long)PK_DT, out_w + (long)k0 * 1024 * 2048, (long)1024 * 2048,
        yob, 1024, (long)PK_YO, 1024, 2048, nullptr, 0);
    // cross-merge accumulate into d_out
    merge_kernel<<<dim3(8, 256), 256, 0, stream>>>(yob, gwb, out, k0, NK);
  }
}

// Round 2
// 2239.363 us; speedup vs baseline: 1.8280x; 1.8280x over previous
//
#include <hip/hip_runtime.h>
#include <math.h>

#define DEV __device__ __forceinline__

typedef unsigned short u16;
typedef short bf16x8 __attribute__((ext_vector_type(8)));
typedef float f32x4 __attribute__((ext_vector_type(4)));

// ---------------- helpers ----------------
DEV float blk_sum(float v, float* sb) {
  #pragma unroll
  for (int o = 32; o > 0; o >>= 1) v += __shfl_down(v, o, 64);
  int lane = threadIdx.x & 63, wid = threadIdx.x >> 6;
  __syncthreads();
  if (lane == 0) sb[wid] = v;
  __syncthreads();
  return sb[0] + sb[1] + sb[2] + sb[3];
}

DEV float silu_f(float x) { return x / (1.f + expf(-x)); }
DEV int imin_i(int a, int b) { return a < b ? a : b; }
DEV int imax_i(int a, int b) { return a > b ? a : b; }

// bf16 round-nearest-even split helpers
DEV u16 bf_rne(float x) {
  unsigned u = __float_as_uint(x);
  return (u16)((u + 0x7fffu + ((u >> 16) & 1u)) >> 16);
}
DEV float bf_val(u16 h) { return __uint_as_float((unsigned)h << 16); }

// async global->LDS, 16 bytes per lane
DEV void gll16(const void* g, void* l) {
  __builtin_amdgcn_global_load_lds(
      (__attribute__((address_space(1))) void*)(g),
      (__attribute__((address_space(3))) void*)(l), 16, 0, 0);
}

#define BN_SCALE 0.9999950000374997f /* 1/sqrt(1+1e-5) */

// ---------------- stage 1: pyramid ----------------

__global__ __launch_bounds__(256) void copyx_kernel(const float* __restrict__ x,
                                                    float* __restrict__ xcT) {
  int idx = blockIdx.x * 256 + threadIdx.x;      // 8*512*256
  int l = idx & 255; int bc = idx >> 8; int c = bc & 511; int b = bc >> 9;
  xcT[((long)b * 256 + l) * 1024 + 512 + c] = x[idx];
}

__global__ __launch_bounds__(256) void pool0_kernel(const float* __restrict__ x,
    const float* __restrict__ pw, const float* __restrict__ bng,
    const float* __restrict__ bnb, float* __restrict__ xcT) {
  __shared__ float sb[8];
  int b = blockIdx.x, o = blockIdx.y, p = threadIdx.x;
  const float* xp = x + (long)b * 512 * 256 + p;
  const float* w = pw + (long)o * 512;
  float s = 0.f;
  for (int c = 0; c < 512; c++) s = fmaf(xp[(long)c * 256], w[c], s);
  float gs = bng[o] * BN_SCALE;
  float v = fminf(fmaxf(fmaf(s, gs, bnb[o]), 0.f), 6.f);
  float m = blk_sum(v, sb) * (1.f / 256.f);
  xcT[((long)b * 256 + p) * 1024 + o] = m;
}

__global__ void apool_kernel(const float* __restrict__ x, float* __restrict__ pooled, int s) {
  int s2 = s * s;
  int idx = blockIdx.x * 256 + threadIdx.x;
  if (idx >= 8 * 512 * s2) return;
  int op = idx % s2; int bc = idx / s2;
  int oh = op / s, ow = op % s;
  int h0 = oh * 16 / s, h1 = (oh * 16 + 16 + s - 1) / s;
  int w0 = ow * 16 / s, w1 = (ow * 16 + 16 + s - 1) / s;
  const float* xp = x + (long)bc * 256;
  float sum = 0.f;
  for (int h = h0; h < h1; h++)
    for (int w = w0; w < w1; w++) sum += xp[h * 16 + w];
  pooled[(long)bc * s2 + op] = sum / (float)((h1 - h0) * (w1 - w0));
}

__global__ void cbr_kernel(const float* __restrict__ pooled, const float* __restrict__ pw_i,
    const float* __restrict__ bng_i, const float* __restrict__ bnb_i,
    float* __restrict__ ys, int s2) {
  int b = blockIdx.x, o = blockIdx.y, p = threadIdx.x;
  if (p >= s2) return;
  const float* pp = pooled + (long)b * 512 * s2 + p;
  const float* w = pw_i + (long)o * 512;
  float sum = 0.f;
  for (int c = 0; c < 512; c++) sum = fmaf(pp[(long)c * s2], w[c], sum);
  float gs = bng_i[o] * BN_SCALE;
  ys[((long)b * 128 + o) * s2 + p] = fminf(fmaxf(fmaf(sum, gs, bnb_i[o]), 0.f), 6.f);
}

__global__ void resize_kernel(const float* __restrict__ ys, float* __restrict__ xcT,
                              int s, int ch0) {
  int b = blockIdx.x, o = blockIdx.y, t = threadIdx.x;
  int h = t >> 4, w = t & 15;
  float scale = (float)s / 16.f;
  float sh = (h + 0.5f) * scale - 0.5f;
  float sw = (w + 0.5f) * scale - 0.5f;
  int h0 = (int)floorf(sh); float fh = sh - (float)h0;
  int w0 = (int)floorf(sw); float fw = sw - (float)w0;
  int ha = imin_i(imax_i(h0, 0), s - 1), hb = imin_i(imax_i(h0 + 1, 0), s - 1);
  int wa = imin_i(imax_i(w0, 0), s - 1), wb = imin_i(imax_i(w0 + 1, 0), s - 1);
  const float* yp = ys + ((long)b * 128 + o) * s * s;
  float v = (1.f - fh) * ((1.f - fw) * yp[ha * s + wa] + fw * yp[ha * s + wb]) +
            fh * ((1.f - fw) * yp[hb * s + wa] + fw * yp[hb * s + wb]);
  xcT[((long)b * 256 + t) * 1024 + ch0 + o] = v;
}

__global__ __launch_bounds__(256) void xcmean_kernel(const float* __restrict__ xcT,
                                                     float* __restrict__ xm) {
  int idx = blockIdx.x * 256 + threadIdx.x;   // 8192
  int c = idx & 1023; int b = idx >> 10;
  const float* p = xcT + (long)b * 256 * 1024 + c;
  float s = 0.f;
  for (int l = 0; l < 256; l++) s += p[(long)l * 1024];
  xm[idx] = s * (1.f / 256.f);
}

__global__ void gate_kernel(const float* __restrict__ xm, const float* __restrict__ gww,
                            float* __restrict__ gwout) {
  __shared__ float lg[64];
  int t = threadIdx.x;          // 64 threads
  int b = t >> 3, j = t & 7;
  const float* xb = xm + b * 1024;
  const float* wj = gww + j * 1024;
  float s = 0.f;
  for (int c = 0; c < 1024; c++) s = fmaf(xb[c], wj[c], s);
  lg[t] = s;
  __syncthreads();
  if (t < 8) {
    float v[8], mx = -1e30f;
    for (int i = 0; i < 8; i++) { v[i] = lg[t * 8 + i]; mx = fmaxf(mx, v[i]); }
    float den = 0.f;
    for (int i = 0; i < 8; i++) { v[i] = expf(v[i] - mx); den += v[i]; }
    float inv = 1.f / den;
    float out[8], tmp[8];
    for (int i = 0; i < 8; i++) { out[i] = 0.f; tmp[i] = v[i] * inv; }
    for (int it = 0; it < 4; it++) {
      int bi = 0; float bv = tmp[0];
      for (int i = 1; i < 8; i++) if (tmp[i] > bv) { bv = tmp[i]; bi = i; }
      out[bi] = bv; tmp[bi] = -1e30f;
    }
    for (int i = 0; i < 8; i++) gwout[t * 8 + i] = out[i];
  }
}

// ---------------- stage 2: cross-scan + fd_gate (writes split-bf16 planes) ------

DEV int scan_src(int k, int l) {
  switch (k) {
    case 0: return l;
    case 1: return ((l & 15) << 4) | (l >> 4);
    case 2: return 255 - l;
    case 3: { int l2 = 255 - l; return ((l2 & 15) << 4) | (l2 >> 4); }
    case 4: { int h = l & 15, w = l >> 4; return (h << 4) | ((h + w) & 15); }
    case 5: { int h = l & 15, w = l >> 4; return (h << 4) | ((w - h) & 15); }
    case 6: { int l2 = 255 - l; int h = l2 & 15, w = l2 >> 4; return (h << 4) | ((h + w) & 15); }
    default:{ int l2 = 255 - l; int h = l2 & 15, w = l2 >> 4; return (h << 4) | ((w - h) & 15); }
  }
}

__global__ __launch_bounds__(256) void fd_gate_kernel(const float* __restrict__ xcT,
    const float* __restrict__ lng, const float* __restrict__ lnb,
    const float* __restrict__ fsc, u16* __restrict__ xghi, u16* __restrict__ xglo, int k0) {
  __shared__ float sb[8];
  int l = blockIdx.x;
  int rg = blockIdx.y;                 // kk*8 + b
  int kk = rg >> 3, b = rg & 7;
  int k = k0 + kk;
  int t = threadIdx.x;
  int p = scan_src(k, l);
  float4 cv = *((const float4*)(xcT + ((long)b * 256 + p) * 1024) + t);
  float4 pv = make_float4(0.f, 0.f, 0.f, 0.f);
  if (l > 0) {
    int pm = scan_src(k, l - 1);
    pv = *((const float4*)(xcT + ((long)b * 256 + pm) * 1024) + t);
  }
  float d0 = cv.x - pv.x, d1 = cv.y - pv.y, d2 = cv.z - pv.z, d3 = cv.w - pv.w;
  float mu = blk_sum(d0 + d1 + d2 + d3, sb) * (1.f / 1024.f);
  float e0 = d0 - mu, e1 = d1 - mu, e2 = d2 - mu, e3 = d3 - mu;
  float var = blk_sum(e0*e0 + e1*e1 + e2*e2 + e3*e3, sb) * (1.f / 1024.f);
  float rstd = rsqrtf(var + 1e-5f);
  float4 g4 = *((const float4*)lng + t);
  float4 b4 = *((const float4*)lnb + t);
  float n0 = fmaf(e0 * rstd, g4.x, b4.x);
  float n1 = fmaf(e1 * rstd, g4.y, b4.y);
  float n2 = fmaf(e2 * rstd, g4.z, b4.z);
  float n3 = fmaf(e3 * rstd, g4.w, b4.w);
  float ss = blk_sum(n0*n0 + n1*n1 + n2*n2 + n3*n3, sb);
  float nd = sqrtf(ss) * fsc[0];
  float gate = 0.2f + 0.8f * tanhf(fabsf(nd));
  float o0 = cv.x * gate, o1 = cv.y * gate, o2 = cv.z * gate, o3 = cv.w * gate;
  ushort4 h4, l4;
  h4.x = bf_rne(o0); l4.x = bf_rne(o0 - bf_val(h4.x));
  h4.y = bf_rne(o1); l4.y = bf_rne(o1 - bf_val(h4.y));
  h4.z = bf_rne(o2); l4.z = bf_rne(o2 - bf_val(h4.z));
  h4.w = bf_rne(o3); l4.w = bf_rne(o3 - bf_val(h4.w));
  long off = ((long)rg * 256 + l) * 1024;
  ((ushort4*)(xghi + off))[t] = h4;
  ((ushort4*)(xglo + off))[t] = l4;
}

// ---------------- split fp32 -> (hi, lo) bf16 planes ----------------
__global__ __launch_bounds__(256) void split_kernel(const float* __restrict__ src,
    u16* __restrict__ hi, u16* __restrict__ lo, long n4) {
  long i = (long)blockIdx.x * 256 + threadIdx.x;
  if (i >= n4) return;
  float4 v = ((const float4*)src)[i];
  ushort4 h, l;
  h.x = bf_rne(v.x); l.x = bf_rne(v.x - bf_val(h.x));
  h.y = bf_rne(v.y); l.y = bf_rne(v.y - bf_val(h.y));
  h.z = bf_rne(v.z); l.z = bf_rne(v.z - bf_val(h.z));
  h.w = bf_rne(v.w); l.w = bf_rne(v.w - bf_val(h.w));
  ((ushort4*)hi)[i] = h;
  ((ushort4*)lo)[i] = l;
}

// ---------------- split-bf16 MFMA GEMM: C[M,N] = A[M,K] * B[N,K]^T ----------------
// 128x128 tile, BK=32, 256 threads (4 waves, 2x2), 4x4 16x16x32 tiles/wave,
// 3 MFMA per tile pair (hi*hi + hi*lo + lo*hi).  EPI=1: silu for n>=2048 columns.
template<int EPI>
__global__ __launch_bounds__(256) void gemm_x3(
    const u16* __restrict__ Ahi, const u16* __restrict__ Alo, long aS,
    const u16* __restrict__ Bhi, const u16* __restrict__ Blo, long bS,
    float* __restrict__ C, long cS, int K, int ldc) {
  __shared__ u16 As[2][4096];   // [plane][row*32 + k], 128 rows x 32 k
  __shared__ u16 Bs[2][4096];
  const int t = threadIdx.x;
  const int z = blockIdx.z;
  Ahi += (long)z * aS; Alo += (long)z * aS;
  Bhi += (long)z * bS; Blo += (long)z * bS; C += (long)z * cS;
  const long m_blk = (long)blockIdx.x * 128;
  const long n_blk = (long)blockIdx.y * 128;
  const int lane = t & 63, wid = t >> 6;
  const int wm = (wid >> 1) * 64, wn = (wid & 1) * 64;
  const int srow = t >> 2, sseg = (t & 3) * 8;
  const u16* gAh = Ahi + (m_blk + srow) * (long)K + sseg;
  const u16* gAl = Alo + (m_blk + srow) * (long)K + sseg;
  const u16* gBh = Bhi + (n_blk + srow) * (long)K + sseg;
  const u16* gBl = Blo + (n_blk + srow) * (long)K + sseg;
  const int lb = wid * 512;           // ushort offset: wave-uniform, lane*16B dest
  const long k64 = (long)64 * K;
  f32x4 acc[4][4];
  #pragma unroll
  for (int r = 0; r < 4; r++)
    #pragma unroll
    for (int c = 0; c < 4; c++) acc[r][c] = (f32x4)0.f;
  const int a_m = lane & 15, a_k = (lane >> 4) * 8;

  for (int kt = 0; kt < K; kt += 32) {
    __syncthreads();
    gll16(gAh + kt,        &As[0][lb]);
    gll16(gAh + kt + k64,  &As[0][lb + 2048]);
    gll16(gAl + kt,        &As[1][lb]);
    gll16(gAl + kt + k64,  &As[1][lb + 2048]);
    gll16(gBh + kt,        &Bs[0][lb]);
    gll16(gBh + kt + k64,  &Bs[0][lb + 2048]);
    gll16(gBl + kt,        &Bs[1][lb]);
    gll16(gBl + kt + k64,  &Bs[1][lb + 2048]);
    __syncthreads();
    bf16x8 ah[4], al[4], bh[4], bl[4];
    #pragma unroll
    for (int r = 0; r < 4; r++) {
      int row = wm + r * 16 + a_m;
      ah[r] = *(const bf16x8*)&As[0][row * 32 + a_k];
      al[r] = *(const bf16x8*)&As[1][row * 32 + a_k];
    }
    #pragma unroll
    for (int c = 0; c < 4; c++) {
      int row = wn + c * 16 + a_m;
      bh[c] = *(const bf16x8*)&Bs[0][row * 32 + a_k];
      bl[c] = *(const bf16x8*)&Bs[1][row * 32 + a_k];
    }
    #pragma unroll
    for (int r = 0; r < 4; r++)
      #pragma unroll
      for (int c = 0; c < 4; c++) {
        acc[r][c] = __builtin_amdgcn_mfma_f32_16x16x32_bf16(ah[r], bh[c], acc[r][c], 0, 0, 0);
        acc[r][c] = __builtin_amdgcn_mfma_f32_16x16x32_bf16(ah[r], bl[c], acc[r][c], 0, 0, 0);
        acc[r][c] = __builtin_amdgcn_mfma_f32_16x16x32_bf16(al[r], bh[c], acc[r][c], 0, 0, 0);
      }
  }
  const bool dosilu = (EPI == 1) && (n_blk >= 2048);
  const int c_col = lane & 15, c_row = (lane >> 4) * 4;
  #pragma unroll
  for (int r = 0; r < 4; r++) {
    long row0 = m_blk + wm + r * 16 + c_row;
    #pragma unroll
    for (int c = 0; c < 4; c++) {
      long col = n_blk + wn + c * 16 + c_col;
      float* cp = C + row0 * ldc + col;
      #pragma unroll
      for (int q = 0; q < 4; q++) {
        float v = acc[r][c][q];
        if (dosilu) v = silu_f(v);
        cp[(long)q * ldc] = v;
      }
    }
  }
}

// ---------------- fp32 tiled GEMM (small): C[M,N] = A[M,K] * B[N,K]^T -----------
template<int EPI>
__global__ __launch_bounds__(256) void gemm_nt(
    const float* __restrict__ A, long lda, long aK,
    const float* __restrict__ Bw, long bK,
    float* __restrict__ C, long ldc, long cK,
    int N, int Kd,
    const float* __restrict__ bias, long biasK) {
  __shared__ float As2[16][132];
  __shared__ float Bs2[16][68];
  const int t = threadIdx.x;
  const int kk = blockIdx.z;
  A += (long)kk * aK; Bw += (long)kk * bK; C += (long)kk * cK;
  if (EPI == 1) bias += (long)kk * biasK;
  const int m_blk = blockIdx.x * 128;
  const int n_blk = blockIdx.y * 64;
  const int tx = t & 15, ty = t >> 4;
  const int aq = t & 3, ar = t >> 2;
  float acc[8][4];
  #pragma unroll
  for (int i = 0; i < 8; i++)
    #pragma unroll
    for (int j = 0; j < 4; j++) acc[i][j] = 0.f;

  for (int kt = 0; kt < Kd; kt += 16) {
    float4 a0 = *(const float4*)(A + (long)(m_blk + ar) * lda + kt + aq * 4);
    float4 a1 = *(const float4*)(A + (long)(m_blk + 64 + ar) * lda + kt + aq * 4);
    float4 b0 = make_float4(0.f, 0.f, 0.f, 0.f);
    int bn = n_blk + ar;
    if (bn < N) b0 = *(const float4*)(Bw + (long)bn * Kd + kt + aq * 4);
    __syncthreads();
    As2[aq*4+0][ar] = a0.x; As2[aq*4+1][ar] = a0.y; As2[aq*4+2][ar] = a0.z; As2[aq*4+3][ar] = a0.w;
    As2[aq*4+0][64+ar] = a1.x; As2[aq*4+1][64+ar] = a1.y; As2[aq*4+2][64+ar] = a1.z; As2[aq*4+3][64+ar] = a1.w;
    Bs2[aq*4+0][ar] = b0.x; Bs2[aq*4+1][ar] = b0.y; Bs2[aq*4+2][ar] = b0.z; Bs2[aq*4+3][ar] = b0.w;
    __syncthreads();
    #pragma unroll
    for (int k2 = 0; k2 < 16; k2++) {
      float av[8], bv[4];
      #pragma unroll
      for (int i = 0; i < 8; i++) av[i] = As2[k2][ty * 8 + i];
      #pragma unroll
      for (int j = 0; j < 4; j++) bv[j] = Bs2[k2][tx * 4 + j];
      #pragma unroll
      for (int i = 0; i < 8; i++)
        #pragma unroll
        for (int j = 0; j < 4; j++) acc[i][j] = fmaf(av[i], bv[j], acc[i][j]);
    }
  }
  #pragma unroll
  for (int i = 0; i < 8; i++) {
    long m = m_blk + ty * 8 + i;
    #pragma unroll
    for (int j = 0; j < 4; j++) {
      int n = n_blk + tx * 4 + j;
      if (n < N) {
        float v = acc[i][j];
        if (EPI == 1) {
          v += bias[n];
          v = log1pf(expf(-fabsf(v))) + fmaxf(v, 0.f);   // softplus
        }
        C[m * ldc + n] = v;
      }
    }
  }
}

// ---------------- causal depthwise conv (kernel 4) + silu, in place over u half --
__global__ __launch_bounds__(256) void conv_silu_kernel(float* uz,
    const float* __restrict__ cw, const float* __restrict__ cb, int k0) {
  long tid = (long)blockIdx.x * 256 + threadIdx.x;  // NK*8*2048
  int d = (int)(tid & 2047);
  long rg = tid >> 11;                               // kk*8 + b
  int k = k0 + (int)(rg >> 3);
  const float* w = cw + ((long)k * 2048 + d) * 4;
  float w0 = w[0], w1 = w[1], w2 = w[2], w3 = w[3];
  float bias = cb[(long)k * 2048 + d];
  float* base = uz + rg * 256 * 4096 + d;
  float x0 = 0.f, x1 = 0.f, x2 = 0.f;
  #pragma unroll 4
  for (int l = 0; l < 256; l++) {
    float x3 = base[(long)l * 4096];
    float v = bias + w0 * x0 + w1 * x1 + w2 * x2 + w3 * x3;
    base[(long)l * 4096] = silu_f(v);
    x0 = x1; x1 = x2; x2 = x3;
  }
}

// ---------------- selective scan + fused epilogue -> split-bf16 y planes --------
__global__ __launch_bounds__(256) void scan_kernel(
    const float* __restrict__ dt, const float* __restrict__ uz,
    const float* __restrict__ xdbl, const float* __restrict__ A_log,
    const float* __restrict__ Dp, u16* __restrict__ yhi, u16* __restrict__ ylo, int k0) {
  int t = threadIdx.x;
  int d = blockIdx.x * 256 + t;
  int rg = blockIdx.y;                 // kk*8 + b
  int k = k0 + (rg >> 3);
  float Av[16];
  const float* Ap = A_log + ((long)k * 2048 + d) * 16;
  #pragma unroll
  for (int s = 0; s < 16; s++) Av[s] = -expf(Ap[s]);
  float dp = Dp[(long)k * 2048 + d];
  __shared__ float BC[8][32];
  float h[16];
  #pragma unroll
  for (int s = 0; s < 16; s++) h[s] = 0.f;
  long rbase = (long)rg * 256;
  for (int l8 = 0; l8 < 256; l8 += 8) {
    __syncthreads();
    BC[t >> 5][t & 31] = xdbl[(rbase + l8 + (t >> 5)) * 96 + 64 + (t & 31)];
    __syncthreads();
    #pragma unroll
    for (int j = 0; j < 8; j++) {
      long r = rbase + l8 + j;
      float dtv = dt[r * 2048 + d];
      float uv = uz[r * 4096 + d];
      float zs = uz[r * 4096 + 2048 + d];   // already silu'ed
      float dtu = dtv * uv;
      float y = 0.f;
      #pragma unroll
      for (int s = 0; s < 16; s++) {
        float dA = expf(dtv * Av[s]);
        h[s] = fmaf(dA, h[s], dtu * BC[j][s]);
        y = fmaf(h[s], BC[j][16 + s], y);
      }
      float ov = (y + uv * dp) * zs;
      u16 hv = bf_rne(ov);
      yhi[r * 2048 + d] = hv;
      ylo[r * 2048 + d] = bf_rne(ov - bf_val(hv));
    }
  }
}

// ---------------- cross merge (accumulating per direction group) ----------------
__global__ __launch_bounds__(256) void merge_kernel(const float* __restrict__ yo,
    const float* __restrict__ gw, float* __restrict__ out, int k0, int NK) {
  int b = blockIdx.x; int c0 = blockIdx.y * 4; int t = threadIdx.x;
  int h = t >> 4, w = t & 15;
  int l0 = t;
  int l1 = (w << 4) | h;
  int l4 = (((w - h) & 15) << 4) | h;
  int l5 = (((w + h) & 15) << 4) | h;
  int lk[8] = { l0, l1, 255 - l0, 255 - l1, l4, l5, 255 - l4, 255 - l5 };
  float a0 = 0.f, a1 = 0.f, a2 = 0.f, a3 = 0.f;
  for (int kk = 0; kk < NK; kk++) {
    int k = k0 + kk;
    float g = gw[b * 8 + k];
    const float4 p = *(const float4*)(yo + (((long)kk * 8 + b) * 256 + lk[k]) * 1024 + c0);
    a0 = fmaf(g, p.x, a0); a1 = fmaf(g, p.y, a1); a2 = fmaf(g, p.z, a2); a3 = fmaf(g, p.w, a3);
  }
  float* op = out + ((long)b * 1024 + c0) * 256 + t;
  if (k0 == 0) { op[0] = a0; op[256] = a1; op[512] = a2; op[768] = a3; }
  else         { op[0] += a0; op[256] += a1; op[512] += a2; op[768] += a3; }
}

// ---------------- host ----------------
extern "C" void kernel_launch(void* const* d_in, const int* in_sizes, int n_in,
                              void* d_out, int out_size, void* d_ws, size_t ws_size,
                              hipStream_t stream) {
  (void)in_sizes; (void)n_in; (void)out_size;
  const float* x      = (const float*)d_in[0];
  const float* pw     = (const float*)d_in[1];
  const float* bn_g   = (const float*)d_in[2];
  const float* bn_b   = (const float*)d_in[3];
  const float* gate_w = (const float*)d_in[4];
  const float* ln_g   = (const float*)d_in[5];
  const float* ln_b   = (const float*)d_in[6];
  const float* fd_s   = (const float*)d_in[7];
  const float* in_w   = (const float*)d_in[8];
  const float* cw     = (const float*)d_in[9];
  const float* cb     = (const float*)d_in[10];
  const float* xp_w   = (const float*)d_in[11];
  const float* dtp_w  = (const float*)d_in[12];
  const float* dtp_b  = (const float*)d_in[13];
  const float* A_log  = (const float*)d_in[14];
  const float* D_p    = (const float*)d_in[15];
  const float* out_w  = (const float*)d_in[16];
  float* out = (float*)d_out;
  float* ws = (float*)d_ws;

  size_t off = 0;
  auto alloc = [&](size_t n) { float* p = ws + off; off += n; return p; };
  float* xcT    = alloc(2097152);        // (b, l, 1024)
  float* pooled = alloc((size_t)8 * 512 * 169);
  float* ysb    = alloc((size_t)8 * 128 * 169);
  float* xm     = alloc(8192);
  float* gwb    = alloc(64);
  const size_t fixed = off;

  // per-direction float counts
  const size_t PK_XGP  = 1048576;   // one xg bf16 plane (2048x1024 u16)
  const size_t PK_UZ   = 8388608;   // uz fp32 (2048x4096)
  const size_t PK_DT   = 4194304;   // dt fp32 (2048x2048)
  const size_t PK_YP   = 2097152;   // one y bf16 plane (2048x2048 u16)
  const size_t PK_XD   = 196608;    // x_dbl fp32 (2048x96)
  const size_t PK_YO   = 2097152;   // yo fp32 (2048x1024)
  const size_t PK_INWP = 2097152;   // one in_w bf16 plane (4096x1024 u16)
  const size_t PK_OUWP = 1048576;   // one out_w bf16 plane (1024x2048 u16)
  const size_t perk = 2*PK_XGP + PK_UZ + PK_DT + 2*PK_YP + PK_XD + PK_YO
                    + 2*PK_INWP + 2*PK_OUWP;
  const size_t avail = ws_size / sizeof(float);
  int NK = 8;
  while (NK > 1 && fixed + perk * (size_t)NK > avail) NK >>= 1;

  u16* xghi  = (u16*)alloc(PK_XGP * NK);
  u16* xglo  = (u16*)alloc(PK_XGP * NK);
  float* uzb = alloc(PK_UZ * NK);
  float* dtb = alloc(PK_DT * NK);
  u16* yhi   = (u16*)alloc(PK_YP * NK);
  u16* ylo   = (u16*)alloc(PK_YP * NK);
  float* xdb = alloc(PK_XD * NK);
  float* yob = alloc(PK_YO * NK);
  u16* inwhi = (u16*)alloc(PK_INWP * NK);
  u16* inwlo = (u16*)alloc(PK_INWP * NK);
  u16* ouwhi = (u16*)alloc(PK_OUWP * NK);
  u16* ouwlo = (u16*)alloc(PK_OUWP * NK);

  // stage 1: pyramid + concat
  copyx_kernel<<<4096, 256, 0, stream>>>(x, xcT);
  pool0_kernel<<<dim3(8, 128), 256, 0, stream>>>(x, pw, bn_g, bn_b, xcT);
  const int svals[3] = {5, 9, 13};
  for (int i = 0; i < 3; i++) {
    int s = svals[i], s2 = s * s;
    int tot = 8 * 512 * s2;
    apool_kernel<<<(tot + 255) / 256, 256, 0, stream>>>(x, pooled, s);
    cbr_kernel<<<dim3(8, 128), 256, 0, stream>>>(pooled, pw + (long)(i + 1) * 128 * 512,
                                                 bn_g + (i + 1) * 128, bn_b + (i + 1) * 128,
                                                 ysb, s2);
    resize_kernel<<<dim3(8, 128), 256, 0, stream>>>(ysb, xcT, s, 128 * (i + 1));
  }
  xcmean_kernel<<<32, 256, 0, stream>>>(xcT, xm);
  gate_kernel<<<1, 64, 0, stream>>>(xm, gate_w, gwb);

  // stage 2: per-direction groups
  for (int k0 = 0; k0 < 8; k0 += NK) {
    // split this group's weights into bf16 hi/lo planes
    {
      long n4 = (long)NK * 4096 * 1024 / 4;
      split_kernel<<<(int)((n4 + 255) / 256), 256, 0, stream>>>(
          in_w + (long)k0 * 4096 * 1024, inwhi, inwlo, n4);
      long m4 = (long)NK * 1024 * 2048 / 4;
      split_kernel<<<(int)((m4 + 255) / 256), 256, 0, stream>>>(
          out_w + (long)k0 * 1024 * 2048, ouwhi, ouwlo, m4);
    }
    fd_gate_kernel<<<dim3(256, NK * 8), 256, 0, stream>>>(xcT, ln_g, ln_b, fd_s,
                                                          xghi, xglo, k0);
    // uz = xg @ in_w[k].T  (N=4096; silu applied to z half)
    gemm_x3<1><<<dim3(16, 32, NK), 256, 0, stream>>>(
        xghi, xglo, (long)2 * PK_XGP,
        inwhi, inwlo, (long)2 * PK_INWP,
        uzb, (long)PK_UZ, 1024, 4096);
    conv_silu_kernel<<<NK * 64, 256, 0, stream>>>(uzb, cw, cb, k0);
    // x_dbl = u @ xp_w[k].T  (N=96)
    gemm_nt<0><<<dim3(16, 2, NK), 256, 0, stream>>>(
        uzb, 4096, (long)PK_UZ, xp_w + (long)k0 * 96 * 2048, (long)96 * 2048,
        xdb, 96, (long)PK_XD, 96, 2048, nullptr, 0);
    // dt = softplus(x_dbl[:, :64] @ dtp_w[k].T + dtp_b[k])
    gemm_nt<1><<<dim3(16, 32, NK), 256, 0, stream>>>(
        xdb, 96, (long)PK_XD, dtp_w + (long)k0 * 2048 * 64, (long)2048 * 64,
        dtb, 2048, (long)PK_DT, 2048, 64, dtp_b + (long)k0 * 2048, 2048);
    // selective scan + (y + u*Dp)*silu(z) -> split-bf16 y planes
    scan_kernel<<<dim3(8, NK * 8), 256, 0, stream>>>(dtb, uzb, xdb, A_log, D_p,
                                                     yhi, ylo, k0);
    // y_out = y @ out_w[k].T  (N=1024)
    gemm_x3<0><<<dim3(16, 8, NK), 256, 0, stream>>>(
        yhi, ylo, (long)2 * PK_YP,
        ouwhi, ouwlo, (long)2 * PK_OUWP,
        yob, (long)PK_YO, 2048, 1024);
    // cross-merge accumulate into d_out
    merge_kernel<<<dim3(8, 256), 256, 0, stream>>>(yob, gwb, out, k0, NK);
  }
}

// Round 3
// 1980.451 us; speedup vs baseline: 2.0669x; 1.1307x over previous
//
#include <hip/hip_runtime.h>
#include <math.h>

#define DEV __device__ __forceinline__

typedef unsigned short u16;
typedef short bf16x8 __attribute__((ext_vector_type(8)));
typedef float f32x4 __attribute__((ext_vector_type(4)));

// ---------------- helpers ----------------
DEV float blk_sum(float v, float* sb) {
  #pragma unroll
  for (int o = 32; o > 0; o >>= 1) v += __shfl_down(v, o, 64);
  int lane = threadIdx.x & 63, wid = threadIdx.x >> 6;
  __syncthreads();
  if (lane == 0) sb[wid] = v;
  __syncthreads();
  return sb[0] + sb[1] + sb[2] + sb[3];
}

DEV float silu_f(float x) { return x / (1.f + expf(-x)); }
DEV int imin_i(int a, int b) { return a < b ? a : b; }
DEV int imax_i(int a, int b) { return a > b ? a : b; }

// bf16 round-nearest-even split helpers
DEV u16 bf_rne(float x) {
  unsigned u = __float_as_uint(x);
  return (u16)((u + 0x7fffu + ((u >> 16) & 1u)) >> 16);
}
DEV float bf_val(u16 h) { return __uint_as_float((unsigned)h << 16); }

// async global->LDS, 16 bytes per lane
DEV void gll16(const void* g, void* l) {
  __builtin_amdgcn_global_load_lds(
      (__attribute__((address_space(1))) void*)(g),
      (__attribute__((address_space(3))) void*)(l), 16, 0, 0);
}

#define BN_SCALE 0.9999950000374997f /* 1/sqrt(1+1e-5) */

// ---------------- stage 1: pyramid ----------------

__global__ __launch_bounds__(256) void copyx_kernel(const float* __restrict__ x,
                                                    float* __restrict__ xcT) {
  int idx = blockIdx.x * 256 + threadIdx.x;      // 8*512*256
  int l = idx & 255; int bc = idx >> 8; int c = bc & 511; int b = bc >> 9;
  xcT[((long)b * 256 + l) * 1024 + 512 + c] = x[idx];
}

__global__ __launch_bounds__(256) void pool0_kernel(const float* __restrict__ x,
    const float* __restrict__ pw, const float* __restrict__ bng,
    const float* __restrict__ bnb, float* __restrict__ xcT) {
  __shared__ float sb[8];
  int b = blockIdx.x, o = blockIdx.y, p = threadIdx.x;
  const float* xp = x + (long)b * 512 * 256 + p;
  const float* w = pw + (long)o * 512;
  float s = 0.f;
  for (int c = 0; c < 512; c++) s = fmaf(xp[(long)c * 256], w[c], s);
  float gs = bng[o] * BN_SCALE;
  float v = fminf(fmaxf(fmaf(s, gs, bnb[o]), 0.f), 6.f);
  float m = blk_sum(v, sb) * (1.f / 256.f);
  xcT[((long)b * 256 + p) * 1024 + o] = m;
}

__global__ void apool_kernel(const float* __restrict__ x, float* __restrict__ pooled, int s) {
  int s2 = s * s;
  int idx = blockIdx.x * 256 + threadIdx.x;
  if (idx >= 8 * 512 * s2) return;
  int op = idx % s2; int bc = idx / s2;
  int oh = op / s, ow = op % s;
  int h0 = oh * 16 / s, h1 = (oh * 16 + 16 + s - 1) / s;
  int w0 = ow * 16 / s, w1 = (ow * 16 + 16 + s - 1) / s;
  const float* xp = x + (long)bc * 256;
  float sum = 0.f;
  for (int h = h0; h < h1; h++)
    for (int w = w0; w < w1; w++) sum += xp[h * 16 + w];
  pooled[(long)bc * s2 + op] = sum / (float)((h1 - h0) * (w1 - w0));
}

__global__ void cbr_kernel(const float* __restrict__ pooled, const float* __restrict__ pw_i,
    const float* __restrict__ bng_i, const float* __restrict__ bnb_i,
    float* __restrict__ ys, int s2) {
  int b = blockIdx.x, o = blockIdx.y, p = threadIdx.x;
  if (p >= s2) return;
  const float* pp = pooled + (long)b * 512 * s2 + p;
  const float* w = pw_i + (long)o * 512;
  float sum = 0.f;
  for (int c = 0; c < 512; c++) sum = fmaf(pp[(long)c * s2], w[c], sum);
  float gs = bng_i[o] * BN_SCALE;
  ys[((long)b * 128 + o) * s2 + p] = fminf(fmaxf(fmaf(sum, gs, bnb_i[o]), 0.f), 6.f);
}

__global__ void resize_kernel(const float* __restrict__ ys, float* __restrict__ xcT,
                              int s, int ch0) {
  int b = blockIdx.x, o = blockIdx.y, t = threadIdx.x;
  int h = t >> 4, w = t & 15;
  float scale = (float)s / 16.f;
  float sh = (h + 0.5f) * scale - 0.5f;
  float sw = (w + 0.5f) * scale - 0.5f;
  int h0 = (int)floorf(sh); float fh = sh - (float)h0;
  int w0 = (int)floorf(sw); float fw = sw - (float)w0;
  int ha = imin_i(imax_i(h0, 0), s - 1), hb = imin_i(imax_i(h0 + 1, 0), s - 1);
  int wa = imin_i(imax_i(w0, 0), s - 1), wb = imin_i(imax_i(w0 + 1, 0), s - 1);
  const float* yp = ys + ((long)b * 128 + o) * s * s;
  float v = (1.f - fh) * ((1.f - fw) * yp[ha * s + wa] + fw * yp[ha * s + wb]) +
            fh * ((1.f - fw) * yp[hb * s + wa] + fw * yp[hb * s + wb]);
  xcT[((long)b * 256 + t) * 1024 + ch0 + o] = v;
}

__global__ __launch_bounds__(256) void xcmean_kernel(const float* __restrict__ xcT,
                                                     float* __restrict__ xm) {
  int idx = blockIdx.x * 256 + threadIdx.x;   // 8192
  int c = idx & 1023; int b = idx >> 10;
  const float* p = xcT + (long)b * 256 * 1024 + c;
  float s = 0.f;
  for (int l = 0; l < 256; l++) s += p[(long)l * 1024];
  xm[idx] = s * (1.f / 256.f);
}

__global__ void gate_kernel(const float* __restrict__ xm, const float* __restrict__ gww,
                            float* __restrict__ gwout) {
  __shared__ float lg[64];
  int t = threadIdx.x;          // 64 threads
  int b = t >> 3, j = t & 7;
  const float* xb = xm + b * 1024;
  const float* wj = gww + j * 1024;
  float s = 0.f;
  for (int c = 0; c < 1024; c++) s = fmaf(xb[c], wj[c], s);
  lg[t] = s;
  __syncthreads();
  if (t < 8) {
    float v[8], mx = -1e30f;
    for (int i = 0; i < 8; i++) { v[i] = lg[t * 8 + i]; mx = fmaxf(mx, v[i]); }
    float den = 0.f;
    for (int i = 0; i < 8; i++) { v[i] = expf(v[i] - mx); den += v[i]; }
    float inv = 1.f / den;
    float out[8], tmp[8];
    for (int i = 0; i < 8; i++) { out[i] = 0.f; tmp[i] = v[i] * inv; }
    for (int it = 0; it < 4; it++) {
      int bi = 0; float bv = tmp[0];
      for (int i = 1; i < 8; i++) if (tmp[i] > bv) { bv = tmp[i]; bi = i; }
      out[bi] = bv; tmp[bi] = -1e30f;
    }
    for (int i = 0; i < 8; i++) gwout[t * 8 + i] = out[i];
  }
}

// ---------------- stage 2: cross-scan + fd_gate (writes split-bf16 planes) ------

DEV int scan_src(int k, int l) {
  switch (k) {
    case 0: return l;
    case 1: return ((l & 15) << 4) | (l >> 4);
    case 2: return 255 - l;
    case 3: { int l2 = 255 - l; return ((l2 & 15) << 4) | (l2 >> 4); }
    case 4: { int h = l & 15, w = l >> 4; return (h << 4) | ((h + w) & 15); }
    case 5: { int h = l & 15, w = l >> 4; return (h << 4) | ((w - h) & 15); }
    case 6: { int l2 = 255 - l; int h = l2 & 15, w = l2 >> 4; return (h << 4) | ((h + w) & 15); }
    default:{ int l2 = 255 - l; int h = l2 & 15, w = l2 >> 4; return (h << 4) | ((w - h) & 15); }
  }
}

__global__ __launch_bounds__(256) void fd_gate_kernel(const float* __restrict__ xcT,
    const float* __restrict__ lng, const float* __restrict__ lnb,
    const float* __restrict__ fsc, u16* __restrict__ xghi, u16* __restrict__ xglo,
    int k0, const float* __restrict__ gw) {
  __shared__ float sb[8];
  int l = blockIdx.x;
  int rg = blockIdx.y;                 // kk*8 + b
  int kk = rg >> 3, b = rg & 7;
  int k = k0 + kk;
  if (gw[b * 8 + k] == 0.f) return;    // gated-off stream: skip (merge multiplies by 0)
  int t = threadIdx.x;
  int p = scan_src(k, l);
  float4 cv = *((const float4*)(xcT + ((long)b * 256 + p) * 1024) + t);
  float4 pv = make_float4(0.f, 0.f, 0.f, 0.f);
  if (l > 0) {
    int pm = scan_src(k, l - 1);
    pv = *((const float4*)(xcT + ((long)b * 256 + pm) * 1024) + t);
  }
  float d0 = cv.x - pv.x, d1 = cv.y - pv.y, d2 = cv.z - pv.z, d3 = cv.w - pv.w;
  float mu = blk_sum(d0 + d1 + d2 + d3, sb) * (1.f / 1024.f);
  float e0 = d0 - mu, e1 = d1 - mu, e2 = d2 - mu, e3 = d3 - mu;
  float var = blk_sum(e0*e0 + e1*e1 + e2*e2 + e3*e3, sb) * (1.f / 1024.f);
  float rstd = rsqrtf(var + 1e-5f);
  float4 g4 = *((const float4*)lng + t);
  float4 b4 = *((const float4*)lnb + t);
  float n0 = fmaf(e0 * rstd, g4.x, b4.x);
  float n1 = fmaf(e1 * rstd, g4.y, b4.y);
  float n2 = fmaf(e2 * rstd, g4.z, b4.z);
  float n3 = fmaf(e3 * rstd, g4.w, b4.w);
  float ss = blk_sum(n0*n0 + n1*n1 + n2*n2 + n3*n3, sb);
  float nd = sqrtf(ss) * fsc[0];
  float gate = 0.2f + 0.8f * tanhf(fabsf(nd));
  float o0 = cv.x * gate, o1 = cv.y * gate, o2 = cv.z * gate, o3 = cv.w * gate;
  ushort4 h4, l4;
  h4.x = bf_rne(o0); l4.x = bf_rne(o0 - bf_val(h4.x));
  h4.y = bf_rne(o1); l4.y = bf_rne(o1 - bf_val(h4.y));
  h4.z = bf_rne(o2); l4.z = bf_rne(o2 - bf_val(h4.z));
  h4.w = bf_rne(o3); l4.w = bf_rne(o3 - bf_val(h4.w));
  long off = ((long)rg * 256 + l) * 1024;
  ((ushort4*)(xghi + off))[t] = h4;
  ((ushort4*)(xglo + off))[t] = l4;
}

// ---------------- split fp32 -> (hi, lo) bf16 planes ----------------
__global__ __launch_bounds__(256) void split_kernel(const float* __restrict__ src,
    u16* __restrict__ hi, u16* __restrict__ lo, long n4) {
  long i = (long)blockIdx.x * 256 + threadIdx.x;
  if (i >= n4) return;
  float4 v = ((const float4*)src)[i];
  ushort4 h, l;
  h.x = bf_rne(v.x); l.x = bf_rne(v.x - bf_val(h.x));
  h.y = bf_rne(v.y); l.y = bf_rne(v.y - bf_val(h.y));
  h.z = bf_rne(v.z); l.z = bf_rne(v.z - bf_val(h.z));
  h.w = bf_rne(v.w); l.w = bf_rne(v.w - bf_val(h.w));
  ((ushort4*)hi)[i] = h;
  ((ushort4*)lo)[i] = l;
}

// ---------------- split-bf16 MFMA GEMM: C[M,N] = A[M,K] * B[N,K]^T ----------------
// 128x128 tile, BK=32, 256 threads (4 waves, 2x2), 4x4 16x16x32 tiles/wave,
// 3 MFMA per tile pair (hi*hi + hi*lo + lo*hi).  EPI=1: silu for n>=2048 columns.
// A rows are 8 streams x 256: m-block -> batch b; skip block if gw[b,k]==0.
template<int EPI>
__global__ __launch_bounds__(256) void gemm_x3(
    const u16* __restrict__ Ahi, const u16* __restrict__ Alo, long aS,
    const u16* __restrict__ Bhi, const u16* __restrict__ Blo, long bS,
    float* __restrict__ C, long cS, int K, int ldc,
    int k0, const float* __restrict__ gw) {
  const long m_blk = (long)blockIdx.x * 128;
  const int z = blockIdx.z;
  {
    int b = (int)(m_blk >> 8);
    int k = k0 + z;
    if (gw[b * 8 + k] == 0.f) return;
  }
  __shared__ u16 As[2][4096];   // [plane][row*32 + k], 128 rows x 32 k
  __shared__ u16 Bs[2][4096];
  const int t = threadIdx.x;
  Ahi += (long)z * aS; Alo += (long)z * aS;
  Bhi += (long)z * bS; Blo += (long)z * bS; C += (long)z * cS;
  const long n_blk = (long)blockIdx.y * 128;
  const int lane = t & 63, wid = t >> 6;
  const int wm = (wid >> 1) * 64, wn = (wid & 1) * 64;
  const int srow = t >> 2, sseg = (t & 3) * 8;
  const u16* gAh = Ahi + (m_blk + srow) * (long)K + sseg;
  const u16* gAl = Alo + (m_blk + srow) * (long)K + sseg;
  const u16* gBh = Bhi + (n_blk + srow) * (long)K + sseg;
  const u16* gBl = Blo + (n_blk + srow) * (long)K + sseg;
  const int lb = wid * 512;           // ushort offset: wave-uniform, lane*16B dest
  const long k64 = (long)64 * K;
  f32x4 acc[4][4];
  #pragma unroll
  for (int r = 0; r < 4; r++)
    #pragma unroll
    for (int c = 0; c < 4; c++) acc[r][c] = (f32x4)0.f;
  const int a_m = lane & 15, a_k = (lane >> 4) * 8;

  for (int kt = 0; kt < K; kt += 32) {
    __syncthreads();
    gll16(gAh + kt,        &As[0][lb]);
    gll16(gAh + kt + k64,  &As[0][lb + 2048]);
    gll16(gAl + kt,        &As[1][lb]);
    gll16(gAl + kt + k64,  &As[1][lb + 2048]);
    gll16(gBh + kt,        &Bs[0][lb]);
    gll16(gBh + kt + k64,  &Bs[0][lb + 2048]);
    gll16(gBl + kt,        &Bs[1][lb]);
    gll16(gBl + kt + k64,  &Bs[1][lb + 2048]);
    __syncthreads();
    bf16x8 ah[4], al[4], bh[4], bl[4];
    #pragma unroll
    for (int r = 0; r < 4; r++) {
      int row = wm + r * 16 + a_m;
      ah[r] = *(const bf16x8*)&As[0][row * 32 + a_k];
      al[r] = *(const bf16x8*)&As[1][row * 32 + a_k];
    }
    #pragma unroll
    for (int c = 0; c < 4; c++) {
      int row = wn + c * 16 + a_m;
      bh[c] = *(const bf16x8*)&Bs[0][row * 32 + a_k];
      bl[c] = *(const bf16x8*)&Bs[1][row * 32 + a_k];
    }
    #pragma unroll
    for (int r = 0; r < 4; r++)
      #pragma unroll
      for (int c = 0; c < 4; c++) {
        acc[r][c] = __builtin_amdgcn_mfma_f32_16x16x32_bf16(ah[r], bh[c], acc[r][c], 0, 0, 0);
        acc[r][c] = __builtin_amdgcn_mfma_f32_16x16x32_bf16(ah[r], bl[c], acc[r][c], 0, 0, 0);
        acc[r][c] = __builtin_amdgcn_mfma_f32_16x16x32_bf16(al[r], bh[c], acc[r][c], 0, 0, 0);
      }
  }
  const bool dosilu = (EPI == 1) && (n_blk >= 2048);
  const int c_col = lane & 15, c_row = (lane >> 4) * 4;
  #pragma unroll
  for (int r = 0; r < 4; r++) {
    long row0 = m_blk + wm + r * 16 + c_row;
    #pragma unroll
    for (int c = 0; c < 4; c++) {
      long col = n_blk + wn + c * 16 + c_col;
      float* cp = C + row0 * ldc + col;
      #pragma unroll
      for (int q = 0; q < 4; q++) {
        float v = acc[r][c][q];
        if (dosilu) v = silu_f(v);
        cp[(long)q * ldc] = v;
      }
    }
  }
}

// ---------------- fp32 tiled GEMM (small): C[M,N] = A[M,K] * B[N,K]^T -----------
template<int EPI>
__global__ __launch_bounds__(256) void gemm_nt(
    const float* __restrict__ A, long lda, long aK,
    const float* __restrict__ Bw, long bK,
    float* __restrict__ C, long ldc, long cK,
    int N, int Kd,
    const float* __restrict__ bias, long biasK,
    int k0, const float* __restrict__ gw) {
  const int m_blk = blockIdx.x * 128;
  const int kk = blockIdx.z;
  {
    int b = m_blk >> 8;
    if (gw[b * 8 + k0 + kk] == 0.f) return;
  }
  __shared__ float As2[16][132];
  __shared__ float Bs2[16][68];
  const int t = threadIdx.x;
  A += (long)kk * aK; Bw += (long)kk * bK; C += (long)kk * cK;
  if (EPI == 1) bias += (long)kk * biasK;
  const int n_blk = blockIdx.y * 64;
  const int tx = t & 15, ty = t >> 4;
  const int aq = t & 3, ar = t >> 2;
  float acc[8][4];
  #pragma unroll
  for (int i = 0; i < 8; i++)
    #pragma unroll
    for (int j = 0; j < 4; j++) acc[i][j] = 0.f;

  for (int kt = 0; kt < Kd; kt += 16) {
    float4 a0 = *(const float4*)(A + (long)(m_blk + ar) * lda + kt + aq * 4);
    float4 a1 = *(const float4*)(A + (long)(m_blk + 64 + ar) * lda + kt + aq * 4);
    float4 b0 = make_float4(0.f, 0.f, 0.f, 0.f);
    int bn = n_blk + ar;
    if (bn < N) b0 = *(const float4*)(Bw + (long)bn * Kd + kt + aq * 4);
    __syncthreads();
    As2[aq*4+0][ar] = a0.x; As2[aq*4+1][ar] = a0.y; As2[aq*4+2][ar] = a0.z; As2[aq*4+3][ar] = a0.w;
    As2[aq*4+0][64+ar] = a1.x; As2[aq*4+1][64+ar] = a1.y; As2[aq*4+2][64+ar] = a1.z; As2[aq*4+3][64+ar] = a1.w;
    Bs2[aq*4+0][ar] = b0.x; Bs2[aq*4+1][ar] = b0.y; Bs2[aq*4+2][ar] = b0.z; Bs2[aq*4+3][ar] = b0.w;
    __syncthreads();
    #pragma unroll
    for (int k2 = 0; k2 < 16; k2++) {
      float av[8], bv[4];
      #pragma unroll
      for (int i = 0; i < 8; i++) av[i] = As2[k2][ty * 8 + i];
      #pragma unroll
      for (int j = 0; j < 4; j++) bv[j] = Bs2[k2][tx * 4 + j];
      #pragma unroll
      for (int i = 0; i < 8; i++)
        #pragma unroll
        for (int j = 0; j < 4; j++) acc[i][j] = fmaf(av[i], bv[j], acc[i][j]);
    }
  }
  #pragma unroll
  for (int i = 0; i < 8; i++) {
    long m = m_blk + ty * 8 + i;
    #pragma unroll
    for (int j = 0; j < 4; j++) {
      int n = n_blk + tx * 4 + j;
      if (n < N) {
        float v = acc[i][j];
        if (EPI == 1) {
          v += bias[n];
          v = log1pf(expf(-fabsf(v))) + fmaxf(v, 0.f);   // softplus
        }
        C[m * ldc + n] = v;
      }
    }
  }
}

// ---------------- causal depthwise conv (kernel 4) + silu, in place over u half --
__global__ __launch_bounds__(256) void conv_silu_kernel(float* uz,
    const float* __restrict__ cw, const float* __restrict__ cb, int k0,
    const float* __restrict__ gw) {
  long tid = (long)blockIdx.x * 256 + threadIdx.x;  // NK*8*2048
  int d = (int)(tid & 2047);
  long rg = tid >> 11;                               // kk*8 + b
  int k = k0 + (int)(rg >> 3);
  int b = (int)(rg & 7);
  if (gw[b * 8 + k] == 0.f) return;
  const float* w = cw + ((long)k * 2048 + d) * 4;
  float w0 = w[0], w1 = w[1], w2 = w[2], w3 = w[3];
  float bias = cb[(long)k * 2048 + d];
  float* base = uz + rg * 256 * 4096 + d;
  float x0 = 0.f, x1 = 0.f, x2 = 0.f;
  #pragma unroll 4
  for (int l = 0; l < 256; l++) {
    float x3 = base[(long)l * 4096];
    float v = bias + w0 * x0 + w1 * x1 + w2 * x2 + w3 * x3;
    base[(long)l * 4096] = silu_f(v);
    x0 = x1; x1 = x2; x2 = x3;
  }
}

// ---------------- selective scan + fused epilogue -> split-bf16 y planes --------
__global__ __launch_bounds__(256) void scan_kernel(
    const float* __restrict__ dt, const float* __restrict__ uz,
    const float* __restrict__ xdbl, const float* __restrict__ A_log,
    const float* __restrict__ Dp, u16* __restrict__ yhi, u16* __restrict__ ylo,
    int k0, const float* __restrict__ gw) {
  int rg = blockIdx.y;                 // kk*8 + b
  int k = k0 + (rg >> 3);
  int b = rg & 7;
  if (gw[b * 8 + k] == 0.f) return;
  int t = threadIdx.x;
  int d = blockIdx.x * 256 + t;
  float Av[16];
  const float* Ap = A_log + ((long)k * 2048 + d) * 16;
  #pragma unroll
  for (int s = 0; s < 16; s++) Av[s] = -expf(Ap[s]);
  float dp = Dp[(long)k * 2048 + d];
  __shared__ float BC[8][32];
  float h[16];
  #pragma unroll
  for (int s = 0; s < 16; s++) h[s] = 0.f;
  long rbase = (long)rg * 256;
  for (int l8 = 0; l8 < 256; l8 += 8) {
    __syncthreads();
    BC[t >> 5][t & 31] = xdbl[(rbase + l8 + (t >> 5)) * 96 + 64 + (t & 31)];
    __syncthreads();
    #pragma unroll
    for (int j = 0; j < 8; j++) {
      long r = rbase + l8 + j;
      float dtv = dt[r * 2048 + d];
      float uv = uz[r * 4096 + d];
      float zs = uz[r * 4096 + 2048 + d];   // already silu'ed
      float dtu = dtv * uv;
      float y = 0.f;
      #pragma unroll
      for (int s = 0; s < 16; s++) {
        float dA = expf(dtv * Av[s]);
        h[s] = fmaf(dA, h[s], dtu * BC[j][s]);
        y = fmaf(h[s], BC[j][16 + s], y);
      }
      float ov = (y + uv * dp) * zs;
      u16 hv = bf_rne(ov);
      yhi[r * 2048 + d] = hv;
      ylo[r * 2048 + d] = bf_rne(ov - bf_val(hv));
    }
  }
}

// ---------------- cross merge (accumulating per direction group) ----------------
__global__ __launch_bounds__(256) void merge_kernel(const float* __restrict__ yo,
    const float* __restrict__ gw, float* __restrict__ out, int k0, int NK) {
  int b = blockIdx.x; int c0 = blockIdx.y * 4; int t = threadIdx.x;
  int h = t >> 4, w = t & 15;
  int l0 = t;
  int l1 = (w << 4) | h;
  int l4 = (((w - h) & 15) << 4) | h;
  int l5 = (((w + h) & 15) << 4) | h;
  int lk[8] = { l0, l1, 255 - l0, 255 - l1, l4, l5, 255 - l4, 255 - l5 };
  float a0 = 0.f, a1 = 0.f, a2 = 0.f, a3 = 0.f;
  for (int kk = 0; kk < NK; kk++) {
    int k = k0 + kk;
    float g = gw[b * 8 + k];
    if (g == 0.f) continue;      // skipped stream: buffer holds poison, exact 0 contribution
    const float4 p = *(const float4*)(yo + (((long)kk * 8 + b) * 256 + lk[k]) * 1024 + c0);
    a0 = fmaf(g, p.x, a0); a1 = fmaf(g, p.y, a1); a2 = fmaf(g, p.z, a2); a3 = fmaf(g, p.w, a3);
  }
  float* op = out + ((long)b * 1024 + c0) * 256 + t;
  if (k0 == 0) { op[0] = a0; op[256] = a1; op[512] = a2; op[768] = a3; }
  else         { op[0] += a0; op[256] += a1; op[512] += a2; op[768] += a3; }
}

// ---------------- host ----------------
extern "C" void kernel_launch(void* const* d_in, const int* in_sizes, int n_in,
                              void* d_out, int out_size, void* d_ws, size_t ws_size,
                              hipStream_t stream) {
  (void)in_sizes; (void)n_in; (void)out_size;
  const float* x      = (const float*)d_in[0];
  const float* pw     = (const float*)d_in[1];
  const float* bn_g   = (const float*)d_in[2];
  const float* bn_b   = (const float*)d_in[3];
  const float* gate_w = (const float*)d_in[4];
  const float* ln_g   = (const float*)d_in[5];
  const float* ln_b   = (const float*)d_in[6];
  const float* fd_s   = (const float*)d_in[7];
  const float* in_w   = (const float*)d_in[8];
  const float* cw     = (const float*)d_in[9];
  const float* cb     = (const float*)d_in[10];
  const float* xp_w   = (const float*)d_in[11];
  const float* dtp_w  = (const float*)d_in[12];
  const float* dtp_b  = (const float*)d_in[13];
  const float* A_log  = (const float*)d_in[14];
  const float* D_p    = (const float*)d_in[15];
  const float* out_w  = (const float*)d_in[16];
  float* out = (float*)d_out;
  float* ws = (float*)d_ws;

  size_t off = 0;
  auto alloc = [&](size_t n) { float* p = ws + off; off += n; return p; };
  float* xcT    = alloc(2097152);        // (b, l, 1024)
  float* pooled = alloc((size_t)8 * 512 * 169);
  float* ysb    = alloc((size_t)8 * 128 * 169);
  float* xm     = alloc(8192);
  float* gwb    = alloc(64);
  const size_t fixed = off;

  // per-direction float counts
  const size_t PK_XGP  = 1048576;   // one xg bf16 plane (2048x1024 u16)
  const size_t PK_UZ   = 8388608;   // uz fp32 (2048x4096)
  const size_t PK_DT   = 4194304;   // dt fp32 (2048x2048)
  const size_t PK_YP   = 2097152;   // one y bf16 plane (2048x2048 u16)
  const size_t PK_XD   = 196608;    // x_dbl fp32 (2048x96)
  const size_t PK_YO   = 2097152;   // yo fp32 (2048x1024)
  const size_t PK_INWP = 2097152;   // one in_w bf16 plane (4096x1024 u16)
  const size_t PK_OUWP = 1048576;   // one out_w bf16 plane (1024x2048 u16)
  const size_t perk = 2*PK_XGP + PK_UZ + PK_DT + 2*PK_YP + PK_XD + PK_YO
                    + 2*PK_INWP + 2*PK_OUWP;
  const size_t avail = ws_size / sizeof(float);
  int NK = 8;
  while (NK > 1 && fixed + perk * (size_t)NK > avail) NK >>= 1;

  u16* xghi  = (u16*)alloc(PK_XGP * NK);
  u16* xglo  = (u16*)alloc(PK_XGP * NK);
  float* uzb = alloc(PK_UZ * NK);
  float* dtb = alloc(PK_DT * NK);
  u16* yhi   = (u16*)alloc(PK_YP * NK);
  u16* ylo   = (u16*)alloc(PK_YP * NK);
  float* xdb = alloc(PK_XD * NK);
  float* yob = alloc(PK_YO * NK);
  u16* inwhi = (u16*)alloc(PK_INWP * NK);
  u16* inwlo = (u16*)alloc(PK_INWP * NK);
  u16* ouwhi = (u16*)alloc(PK_OUWP * NK);
  u16* ouwlo = (u16*)alloc(PK_OUWP * NK);

  // stage 1: pyramid + concat
  copyx_kernel<<<4096, 256, 0, stream>>>(x, xcT);
  pool0_kernel<<<dim3(8, 128), 256, 0, stream>>>(x, pw, bn_g, bn_b, xcT);
  const int svals[3] = {5, 9, 13};
  for (int i = 0; i < 3; i++) {
    int s = svals[i], s2 = s * s;
    int tot = 8 * 512 * s2;
    apool_kernel<<<(tot + 255) / 256, 256, 0, stream>>>(x, pooled, s);
    cbr_kernel<<<dim3(8, 128), 256, 0, stream>>>(pooled, pw + (long)(i + 1) * 128 * 512,
                                                 bn_g + (i + 1) * 128, bn_b + (i + 1) * 128,
                                                 ysb, s2);
    resize_kernel<<<dim3(8, 128), 256, 0, stream>>>(ysb, xcT, s, 128 * (i + 1));
  }
  xcmean_kernel<<<32, 256, 0, stream>>>(xcT, xm);
  gate_kernel<<<1, 64, 0, stream>>>(xm, gate_w, gwb);

  // stage 2: per-direction groups
  for (int k0 = 0; k0 < 8; k0 += NK) {
    // split this group's weights into bf16 hi/lo planes
    {
      long n4 = (long)NK * 4096 * 1024 / 4;
      split_kernel<<<(int)((n4 + 255) / 256), 256, 0, stream>>>(
          in_w + (long)k0 * 4096 * 1024, inwhi, inwlo, n4);
      long m4 = (long)NK * 1024 * 2048 / 4;
      split_kernel<<<(int)((m4 + 255) / 256), 256, 0, stream>>>(
          out_w + (long)k0 * 1024 * 2048, ouwhi, ouwlo, m4);
    }
    fd_gate_kernel<<<dim3(256, NK * 8), 256, 0, stream>>>(xcT, ln_g, ln_b, fd_s,
                                                          xghi, xglo, k0, gwb);
    // uz = xg @ in_w[k].T  (N=4096; silu applied to z half)
    gemm_x3<1><<<dim3(16, 32, NK), 256, 0, stream>>>(
        xghi, xglo, (long)2 * PK_XGP,
        inwhi, inwlo, (long)2 * PK_INWP,
        uzb, (long)PK_UZ, 1024, 4096, k0, gwb);
    conv_silu_kernel<<<NK * 64, 256, 0, stream>>>(uzb, cw, cb, k0, gwb);
    // x_dbl = u @ xp_w[k].T  (N=96)
    gemm_nt<0><<<dim3(16, 2, NK), 256, 0, stream>>>(
        uzb, 4096, (long)PK_UZ, xp_w + (long)k0 * 96 * 2048, (long)96 * 2048,
        xdb, 96, (long)PK_XD, 96, 2048, nullptr, 0, k0, gwb);
    // dt = softplus(x_dbl[:, :64] @ dtp_w[k].T + dtp_b[k])  (N=64 -> 1 n-block)
    gemm_nt<1><<<dim3(16, 1, NK), 256, 0, stream>>>(
        xdb, 96, (long)PK_XD, dtp_w + (long)k0 * 2048 * 64, (long)2048 * 64,
        dtb, 2048, (long)PK_DT, 2048, 64, dtp_b + (long)k0 * 2048, 2048, k0, gwb);
    // selective scan + (y + u*Dp)*silu(z) -> split-bf16 y planes
    scan_kernel<<<dim3(8, NK * 8), 256, 0, stream>>>(dtb, uzb, xdb, A_log, D_p,
                                                     yhi, ylo, k0, gwb);
    // y_out = y @ out_w[k].T  (N=1024)
    gemm_x3<0><<<dim3(16, 8, NK), 256, 0, stream>>>(
        yhi, ylo, (long)2 * PK_YP,
        ouwhi, ouwlo, (long)2 * PK_OUWP,
        yob, (long)PK_YO, 2048, 1024, k0, gwb);
    // cross-merge accumulate into d_out
    merge_kernel<<<dim3(8, 256), 256, 0, stream>>>(yob, gwb, out, k0, NK);
  }
}

// Round 4
// 1849.612 us; speedup vs baseline: 2.2131x; 1.0707x over previous
//
#include <hip/hip_runtime.h>
#include <math.h>

#define DEV __device__ __forceinline__

typedef unsigned short u16;
typedef short bf16x8 __attribute__((ext_vector_type(8)));
typedef float f32x4 __attribute__((ext_vector_type(4)));

// ---------------- helpers ----------------
DEV float blk_sum(float v, float* sb) {
  #pragma unroll
  for (int o = 32; o > 0; o >>= 1) v += __shfl_down(v, o, 64);
  int lane = threadIdx.x & 63, wid = threadIdx.x >> 6;
  __syncthreads();
  if (lane == 0) sb[wid] = v;
  __syncthreads();
  return sb[0] + sb[1] + sb[2] + sb[3];
}

DEV float silu_f(float x) { return x / (1.f + expf(-x)); }
DEV int imin_i(int a, int b) { return a < b ? a : b; }
DEV int imax_i(int a, int b) { return a > b ? a : b; }

// bf16 round-nearest-even split helpers
DEV u16 bf_rne(float x) {
  unsigned u = __float_as_uint(x);
  return (u16)((u + 0x7fffu + ((u >> 16) & 1u)) >> 16);
}
DEV float bf_val(u16 h) { return __uint_as_float((unsigned)h << 16); }

// async global->LDS, 16 bytes per lane
DEV void gll16(const void* g, void* l) {
  __builtin_amdgcn_global_load_lds(
      (__attribute__((address_space(1))) void*)(g),
      (__attribute__((address_space(3))) void*)(l), 16, 0, 0);
}

#define BN_SCALE 0.9999950000374997f /* 1/sqrt(1+1e-5) */

// ---------------- stage 1: pyramid ----------------

__global__ __launch_bounds__(256) void copyx_kernel(const float* __restrict__ x,
                                                    float* __restrict__ xcT) {
  int idx = blockIdx.x * 256 + threadIdx.x;      // 8*512*256
  int l = idx & 255; int bc = idx >> 8; int c = bc & 511; int b = bc >> 9;
  xcT[((long)b * 256 + l) * 1024 + 512 + c] = x[idx];
}

__global__ __launch_bounds__(256) void pool0_kernel(const float* __restrict__ x,
    const float* __restrict__ pw, const float* __restrict__ bng,
    const float* __restrict__ bnb, float* __restrict__ xcT) {
  __shared__ float sb[8];
  int b = blockIdx.x, o = blockIdx.y, p = threadIdx.x;
  const float* xp = x + (long)b * 512 * 256 + p;
  const float* w = pw + (long)o * 512;
  float s = 0.f;
  for (int c = 0; c < 512; c++) s = fmaf(xp[(long)c * 256], w[c], s);
  float gs = bng[o] * BN_SCALE;
  float v = fminf(fmaxf(fmaf(s, gs, bnb[o]), 0.f), 6.f);
  float m = blk_sum(v, sb) * (1.f / 256.f);
  xcT[((long)b * 256 + p) * 1024 + o] = m;
}

__global__ void apool_kernel(const float* __restrict__ x, float* __restrict__ pooled, int s) {
  int s2 = s * s;
  int idx = blockIdx.x * 256 + threadIdx.x;
  if (idx >= 8 * 512 * s2) return;
  int op = idx % s2; int bc = idx / s2;
  int oh = op / s, ow = op % s;
  int h0 = oh * 16 / s, h1 = (oh * 16 + 16 + s - 1) / s;
  int w0 = ow * 16 / s, w1 = (ow * 16 + 16 + s - 1) / s;
  const float* xp = x + (long)bc * 256;
  float sum = 0.f;
  for (int h = h0; h < h1; h++)
    for (int w = w0; w < w1; w++) sum += xp[h * 16 + w];
  pooled[(long)bc * s2 + op] = sum / (float)((h1 - h0) * (w1 - w0));
}

__global__ void cbr_kernel(const float* __restrict__ pooled, const float* __restrict__ pw_i,
    const float* __restrict__ bng_i, const float* __restrict__ bnb_i,
    float* __restrict__ ys, int s2) {
  int b = blockIdx.x, o = blockIdx.y, p = threadIdx.x;
  if (p >= s2) return;
  const float* pp = pooled + (long)b * 512 * s2 + p;
  const float* w = pw_i + (long)o * 512;
  float sum = 0.f;
  for (int c = 0; c < 512; c++) sum = fmaf(pp[(long)c * s2], w[c], sum);
  float gs = bng_i[o] * BN_SCALE;
  ys[((long)b * 128 + o) * s2 + p] = fminf(fmaxf(fmaf(sum, gs, bnb_i[o]), 0.f), 6.f);
}

__global__ void resize_kernel(const float* __restrict__ ys, float* __restrict__ xcT,
                              int s, int ch0) {
  int b = blockIdx.x, o = blockIdx.y, t = threadIdx.x;
  int h = t >> 4, w = t & 15;
  float scale = (float)s / 16.f;
  float sh = (h + 0.5f) * scale - 0.5f;
  float sw = (w + 0.5f) * scale - 0.5f;
  int h0 = (int)floorf(sh); float fh = sh - (float)h0;
  int w0 = (int)floorf(sw); float fw = sw - (float)w0;
  int ha = imin_i(imax_i(h0, 0), s - 1), hb = imin_i(imax_i(h0 + 1, 0), s - 1);
  int wa = imin_i(imax_i(w0, 0), s - 1), wb = imin_i(imax_i(w0 + 1, 0), s - 1);
  const float* yp = ys + ((long)b * 128 + o) * s * s;
  float v = (1.f - fh) * ((1.f - fw) * yp[ha * s + wa] + fw * yp[ha * s + wb]) +
            fh * ((1.f - fw) * yp[hb * s + wa] + fw * yp[hb * s + wb]);
  xcT[((long)b * 256 + t) * 1024 + ch0 + o] = v;
}

__global__ __launch_bounds__(256) void xcmean_kernel(const float* __restrict__ xcT,
                                                     float* __restrict__ xm) {
  int idx = blockIdx.x * 256 + threadIdx.x;   // 8192
  int c = idx & 1023; int b = idx >> 10;
  const float* p = xcT + (long)b * 256 * 1024 + c;
  float s = 0.f;
  for (int l = 0; l < 256; l++) s += p[(long)l * 1024];
  xm[idx] = s * (1.f / 256.f);
}

__global__ void gate_kernel(const float* __restrict__ xm, const float* __restrict__ gww,
                            float* __restrict__ gwout) {
  __shared__ float lg[64];
  int t = threadIdx.x;          // 64 threads
  int b = t >> 3, j = t & 7;
  const float* xb = xm + b * 1024;
  const float* wj = gww + j * 1024;
  float s = 0.f;
  for (int c = 0; c < 1024; c++) s = fmaf(xb[c], wj[c], s);
  lg[t] = s;
  __syncthreads();
  if (t < 8) {
    float v[8], mx = -1e30f;
    for (int i = 0; i < 8; i++) { v[i] = lg[t * 8 + i]; mx = fmaxf(mx, v[i]); }
    float den = 0.f;
    for (int i = 0; i < 8; i++) { v[i] = expf(v[i] - mx); den += v[i]; }
    float inv = 1.f / den;
    float out[8], tmp[8];
    for (int i = 0; i < 8; i++) { out[i] = 0.f; tmp[i] = v[i] * inv; }
    for (int it = 0; it < 4; it++) {
      int bi = 0; float bv = tmp[0];
      for (int i = 1; i < 8; i++) if (tmp[i] > bv) { bv = tmp[i]; bi = i; }
      out[bi] = bv; tmp[bi] = -1e30f;
    }
    for (int i = 0; i < 8; i++) gwout[t * 8 + i] = out[i];
  }
}

// ---------------- stage 2: cross-scan + fd_gate (writes split-bf16 planes) ------

DEV int scan_src(int k, int l) {
  switch (k) {
    case 0: return l;
    case 1: return ((l & 15) << 4) | (l >> 4);
    case 2: return 255 - l;
    case 3: { int l2 = 255 - l; return ((l2 & 15) << 4) | (l2 >> 4); }
    case 4: { int h = l & 15, w = l >> 4; return (h << 4) | ((h + w) & 15); }
    case 5: { int h = l & 15, w = l >> 4; return (h << 4) | ((w - h) & 15); }
    case 6: { int l2 = 255 - l; int h = l2 & 15, w = l2 >> 4; return (h << 4) | ((h + w) & 15); }
    default:{ int l2 = 255 - l; int h = l2 & 15, w = l2 >> 4; return (h << 4) | ((w - h) & 15); }
  }
}

__global__ __launch_bounds__(256) void fd_gate_kernel(const float* __restrict__ xcT,
    const float* __restrict__ lng, const float* __restrict__ lnb,
    const float* __restrict__ fsc, u16* __restrict__ xghi, u16* __restrict__ xglo,
    int k0, const float* __restrict__ gw) {
  __shared__ float sb[8];
  int l = blockIdx.x;
  int rg = blockIdx.y;                 // kk*8 + b
  int kk = rg >> 3, b = rg & 7;
  int k = k0 + kk;
  if (gw[b * 8 + k] == 0.f) return;    // gated-off stream: skip (merge multiplies by 0)
  int t = threadIdx.x;
  int p = scan_src(k, l);
  float4 cv = *((const float4*)(xcT + ((long)b * 256 + p) * 1024) + t);
  float4 pv = make_float4(0.f, 0.f, 0.f, 0.f);
  if (l > 0) {
    int pm = scan_src(k, l - 1);
    pv = *((const float4*)(xcT + ((long)b * 256 + pm) * 1024) + t);
  }
  float d0 = cv.x - pv.x, d1 = cv.y - pv.y, d2 = cv.z - pv.z, d3 = cv.w - pv.w;
  float mu = blk_sum(d0 + d1 + d2 + d3, sb) * (1.f / 1024.f);
  float e0 = d0 - mu, e1 = d1 - mu, e2 = d2 - mu, e3 = d3 - mu;
  float var = blk_sum(e0*e0 + e1*e1 + e2*e2 + e3*e3, sb) * (1.f / 1024.f);
  float rstd = rsqrtf(var + 1e-5f);
  float4 g4 = *((const float4*)lng + t);
  float4 b4 = *((const float4*)lnb + t);
  float n0 = fmaf(e0 * rstd, g4.x, b4.x);
  float n1 = fmaf(e1 * rstd, g4.y, b4.y);
  float n2 = fmaf(e2 * rstd, g4.z, b4.z);
  float n3 = fmaf(e3 * rstd, g4.w, b4.w);
  float ss = blk_sum(n0*n0 + n1*n1 + n2*n2 + n3*n3, sb);
  float nd = sqrtf(ss) * fsc[0];
  float gate = 0.2f + 0.8f * tanhf(fabsf(nd));
  float o0 = cv.x * gate, o1 = cv.y * gate, o2 = cv.z * gate, o3 = cv.w * gate;
  ushort4 h4, l4;
  h4.x = bf_rne(o0); l4.x = bf_rne(o0 - bf_val(h4.x));
  h4.y = bf_rne(o1); l4.y = bf_rne(o1 - bf_val(h4.y));
  h4.z = bf_rne(o2); l4.z = bf_rne(o2 - bf_val(h4.z));
  h4.w = bf_rne(o3); l4.w = bf_rne(o3 - bf_val(h4.w));
  long off = ((long)rg * 256 + l) * 1024;
  ((ushort4*)(xghi + off))[t] = h4;
  ((ushort4*)(xglo + off))[t] = l4;
}

// ---------------- split fp32 -> (hi, lo) bf16 planes ----------------
__global__ __launch_bounds__(256) void split_kernel(const float* __restrict__ src,
    u16* __restrict__ hi, u16* __restrict__ lo, long n4) {
  long i = (long)blockIdx.x * 256 + threadIdx.x;
  if (i >= n4) return;
  float4 v = ((const float4*)src)[i];
  ushort4 h, l;
  h.x = bf_rne(v.x); l.x = bf_rne(v.x - bf_val(h.x));
  h.y = bf_rne(v.y); l.y = bf_rne(v.y - bf_val(h.y));
  h.z = bf_rne(v.z); l.z = bf_rne(v.z - bf_val(h.z));
  h.w = bf_rne(v.w); l.w = bf_rne(v.w - bf_val(h.w));
  ((ushort4*)hi)[i] = h;
  ((ushort4*)lo)[i] = l;
}

// split + zero-pad xp_w (96x2048 -> 128x2048 rows) into bf16 planes
__global__ __launch_bounds__(256) void xpw_split_kernel(const float* __restrict__ xpw,
    u16* __restrict__ hi, u16* __restrict__ lo, int k0, int NK) {
  long idx = (long)blockIdx.x * 256 + threadIdx.x;   // float4 units
  long per = 128 * 2048 / 4;
  long tot = (long)NK * per;
  if (idx >= tot) return;
  long kk = idx / per;
  long rem = idx - kk * per;
  long row = rem / 512;
  long col4 = rem - row * 512;
  float4 v = make_float4(0.f, 0.f, 0.f, 0.f);
  if (row < 96)
    v = *(const float4*)(xpw + (((long)(k0 + kk) * 96 + row) * 2048) + col4 * 4);
  ushort4 h, l;
  h.x = bf_rne(v.x); l.x = bf_rne(v.x - bf_val(h.x));
  h.y = bf_rne(v.y); l.y = bf_rne(v.y - bf_val(h.y));
  h.z = bf_rne(v.z); l.z = bf_rne(v.z - bf_val(h.z));
  h.w = bf_rne(v.w); l.w = bf_rne(v.w - bf_val(h.w));
  ((ushort4*)hi)[idx] = h;
  ((ushort4*)lo)[idx] = l;
}

// ---------------- split-bf16 MFMA GEMM: C[M,N] = A[M,K] * B[N,K]^T ----------------
// 128x128 tile, BK=32, 256 threads (4 waves, 2x2), 4x4 16x16x32 tiles/wave,
// 3 MFMA per tile pair (hi*hi + hi*lo + lo*hi).  EPI=1: silu for n>=2048 columns.
// A rows are 8 streams x 256: m-block -> batch b; skip block if gw[b,k]==0.
template<int EPI>
__global__ __launch_bounds__(256) void gemm_x3(
    const u16* __restrict__ Ahi, const u16* __restrict__ Alo, long aS,
    const u16* __restrict__ Bhi, const u16* __restrict__ Blo, long bS,
    float* __restrict__ C, long cS, int K, int ldc, int Nlim,
    int k0, const float* __restrict__ gw) {
  const long m_blk = (long)blockIdx.x * 128;
  const int z = blockIdx.z;
  {
    int b = (int)(m_blk >> 8);
    int k = k0 + z;
    if (gw[b * 8 + k] == 0.f) return;
  }
  __shared__ u16 As[2][4096];   // [plane][row*32 + k], 128 rows x 32 k
  __shared__ u16 Bs[2][4096];
  const int t = threadIdx.x;
  Ahi += (long)z * aS; Alo += (long)z * aS;
  Bhi += (long)z * bS; Blo += (long)z * bS; C += (long)z * cS;
  const long n_blk = (long)blockIdx.y * 128;
  const int lane = t & 63, wid = t >> 6;
  const int wm = (wid >> 1) * 64, wn = (wid & 1) * 64;
  const int srow = t >> 2, sseg = (t & 3) * 8;
  const u16* gAh = Ahi + (m_blk + srow) * (long)K + sseg;
  const u16* gAl = Alo + (m_blk + srow) * (long)K + sseg;
  const u16* gBh = Bhi + (n_blk + srow) * (long)K + sseg;
  const u16* gBl = Blo + (n_blk + srow) * (long)K + sseg;
  const int lb = wid * 512;           // ushort offset: wave-uniform, lane*16B dest
  const long k64 = (long)64 * K;
  f32x4 acc[4][4];
  #pragma unroll
  for (int r = 0; r < 4; r++)
    #pragma unroll
    for (int c = 0; c < 4; c++) acc[r][c] = (f32x4)0.f;
  const int a_m = lane & 15, a_k = (lane >> 4) * 8;

  for (int kt = 0; kt < K; kt += 32) {
    __syncthreads();
    gll16(gAh + kt,        &As[0][lb]);
    gll16(gAh + kt + k64,  &As[0][lb + 2048]);
    gll16(gAl + kt,        &As[1][lb]);
    gll16(gAl + kt + k64,  &As[1][lb + 2048]);
    gll16(gBh + kt,        &Bs[0][lb]);
    gll16(gBh + kt + k64,  &Bs[0][lb + 2048]);
    gll16(gBl + kt,        &Bs[1][lb]);
    gll16(gBl + kt + k64,  &Bs[1][lb + 2048]);
    __syncthreads();
    bf16x8 ah[4], al[4], bh[4], bl[4];
    #pragma unroll
    for (int r = 0; r < 4; r++) {
      int row = wm + r * 16 + a_m;
      ah[r] = *(const bf16x8*)&As[0][row * 32 + a_k];
      al[r] = *(const bf16x8*)&As[1][row * 32 + a_k];
    }
    #pragma unroll
    for (int c = 0; c < 4; c++) {
      int row = wn + c * 16 + a_m;
      bh[c] = *(const bf16x8*)&Bs[0][row * 32 + a_k];
      bl[c] = *(const bf16x8*)&Bs[1][row * 32 + a_k];
    }
    #pragma unroll
    for (int r = 0; r < 4; r++)
      #pragma unroll
      for (int c = 0; c < 4; c++) {
        acc[r][c] = __builtin_amdgcn_mfma_f32_16x16x32_bf16(ah[r], bh[c], acc[r][c], 0, 0, 0);
        acc[r][c] = __builtin_amdgcn_mfma_f32_16x16x32_bf16(ah[r], bl[c], acc[r][c], 0, 0, 0);
        acc[r][c] = __builtin_amdgcn_mfma_f32_16x16x32_bf16(al[r], bh[c], acc[r][c], 0, 0, 0);
      }
  }
  const bool dosilu = (EPI == 1) && (n_blk >= 2048);
  const int c_col = lane & 15, c_row = (lane >> 4) * 4;
  #pragma unroll
  for (int r = 0; r < 4; r++) {
    long row0 = m_blk + wm + r * 16 + c_row;
    #pragma unroll
    for (int c = 0; c < 4; c++) {
      long col = n_blk + wn + c * 16 + c_col;
      if (col >= Nlim) continue;
      float* cp = C + row0 * ldc + col;
      #pragma unroll
      for (int q = 0; q < 4; q++) {
        float v = acc[r][c][q];
        if (dosilu) v = silu_f(v);
        cp[(long)q * ldc] = v;
      }
    }
  }
}

// ---------------- fp32 tiled GEMM (small): C[M,N] = A[M,K] * B[N,K]^T -----------
template<int EPI>
__global__ __launch_bounds__(256) void gemm_nt(
    const float* __restrict__ A, long lda, long aK,
    const float* __restrict__ Bw, long bK,
    float* __restrict__ C, long ldc, long cK,
    int N, int Kd,
    const float* __restrict__ bias, long biasK,
    int k0, const float* __restrict__ gw) {
  const int m_blk = blockIdx.x * 128;
  const int kk = blockIdx.z;
  {
    int b = m_blk >> 8;
    if (gw[b * 8 + k0 + kk] == 0.f) return;
  }
  __shared__ float As2[16][132];
  __shared__ float Bs2[16][68];
  const int t = threadIdx.x;
  A += (long)kk * aK; Bw += (long)kk * bK; C += (long)kk * cK;
  if (EPI == 1) bias += (long)kk * biasK;
  const int n_blk = blockIdx.y * 64;
  const int tx = t & 15, ty = t >> 4;
  const int aq = t & 3, ar = t >> 2;
  float acc[8][4];
  #pragma unroll
  for (int i = 0; i < 8; i++)
    #pragma unroll
    for (int j = 0; j < 4; j++) acc[i][j] = 0.f;

  for (int kt = 0; kt < Kd; kt += 16) {
    float4 a0 = *(const float4*)(A + (long)(m_blk + ar) * lda + kt + aq * 4);
    float4 a1 = *(const float4*)(A + (long)(m_blk + 64 + ar) * lda + kt + aq * 4);
    float4 b0 = make_float4(0.f, 0.f, 0.f, 0.f);
    int bn = n_blk + ar;
    if (bn < N) b0 = *(const float4*)(Bw + (long)bn * Kd + kt + aq * 4);
    __syncthreads();
    As2[aq*4+0][ar] = a0.x; As2[aq*4+1][ar] = a0.y; As2[aq*4+2][ar] = a0.z; As2[aq*4+3][ar] = a0.w;
    As2[aq*4+0][64+ar] = a1.x; As2[aq*4+1][64+ar] = a1.y; As2[aq*4+2][64+ar] = a1.z; As2[aq*4+3][64+ar] = a1.w;
    Bs2[aq*4+0][ar] = b0.x; Bs2[aq*4+1][ar] = b0.y; Bs2[aq*4+2][ar] = b0.z; Bs2[aq*4+3][ar] = b0.w;
    __syncthreads();
    #pragma unroll
    for (int k2 = 0; k2 < 16; k2++) {
      float av[8], bv[4];
      #pragma unroll
      for (int i = 0; i < 8; i++) av[i] = As2[k2][ty * 8 + i];
      #pragma unroll
      for (int j = 0; j < 4; j++) bv[j] = Bs2[k2][tx * 4 + j];
      #pragma unroll
      for (int i = 0; i < 8; i++)
        #pragma unroll
        for (int j = 0; j < 4; j++) acc[i][j] = fmaf(av[i], bv[j], acc[i][j]);
    }
  }
  #pragma unroll
  for (int i = 0; i < 8; i++) {
    long m = m_blk + ty * 8 + i;
    #pragma unroll
    for (int j = 0; j < 4; j++) {
      int n = n_blk + tx * 4 + j;
      if (n < N) {
        float v = acc[i][j];
        if (EPI == 1) {
          v += bias[n];
          v = log1pf(expf(-fabsf(v))) + fmaxf(v, 0.f);   // softplus
        }
        C[m * ldc + n] = v;
      }
    }
  }
}

// ------- causal depthwise conv (kernel 4) + silu, L-chunked, -> split-bf16 u ----
// reads pristine uz u-half; writes split-bf16 u into the y planes (free until scan)
__global__ __launch_bounds__(256) void conv_split_kernel(const float* __restrict__ uz,
    const float* __restrict__ cw, const float* __restrict__ cb,
    u16* __restrict__ uhi, u16* __restrict__ ulo, int k0,
    const float* __restrict__ gw) {
  long tid = (long)blockIdx.x * 256 + threadIdx.x;  // NK*8 * 8chunks * 2048
  int d = (int)(tid & 2047);
  int chunk = (int)((tid >> 11) & 7);
  int rg = (int)(tid >> 14);                         // kk*8 + b
  int k = k0 + (rg >> 3);
  int b = rg & 7;
  if (gw[b * 8 + k] == 0.f) return;
  const float* w = cw + ((long)k * 2048 + d) * 4;
  float w0 = w[0], w1 = w[1], w2 = w[2], w3 = w[3];
  float bias = cb[(long)k * 2048 + d];
  long r0 = (long)rg * 256 + chunk * 32;
  float x0 = 0.f, x1 = 0.f, x2 = 0.f;
  if (chunk > 0) {
    x0 = uz[(r0 - 3) * 4096 + d];
    x1 = uz[(r0 - 2) * 4096 + d];
    x2 = uz[(r0 - 1) * 4096 + d];
  }
  #pragma unroll 4
  for (int l = 0; l < 32; l++) {
    long r = r0 + l;
    float x3 = uz[r * 4096 + d];
    float v = bias + w0 * x0 + w1 * x1 + w2 * x2 + w3 * x3;
    float sv = silu_f(v);
    u16 hv = bf_rne(sv);
    uhi[r * 2048 + d] = hv;
    ulo[r * 2048 + d] = bf_rne(sv - bf_val(hv));
    x0 = x1; x1 = x2; x2 = x3;
  }
}

// ---------------- selective scan (s-split x4) + fused epilogue ------------------
// lane = sg*16 + d_local; each thread owns 4 of 16 state channels; y reduced via
// shfl_xor(16/32).  Reads split-bf16 u from y planes, overwrites them with y.
__global__ __launch_bounds__(256) void scan_kernel(
    const float* __restrict__ dt, const float* __restrict__ uz,
    const float* __restrict__ xdbl, const float* __restrict__ A_log,
    const float* __restrict__ Dp, u16* __restrict__ yhi, u16* __restrict__ ylo,
    int k0, const float* __restrict__ gw) {
  int rg = blockIdx.y;                 // kk*8 + b
  int k = k0 + (rg >> 3);
  int b = rg & 7;
  if (gw[b * 8 + k] == 0.f) return;
  int t = threadIdx.x;
  int lane = t & 63, wid = t >> 6;
  int sg = lane >> 4, dl = lane & 15;
  int d = blockIdx.x * 64 + wid * 16 + dl;
  float Av[4];
  const float* Ap = A_log + ((long)k * 2048 + d) * 16 + sg * 4;
  #pragma unroll
  for (int s = 0; s < 4; s++) Av[s] = -expf(Ap[s]);
  float dp = Dp[(long)k * 2048 + d];
  __shared__ float BC[8][32];
  float h[4] = {0.f, 0.f, 0.f, 0.f};
  long rbase = (long)rg * 256;
  for (int l8 = 0; l8 < 256; l8 += 8) {
    __syncthreads();
    BC[t >> 5][t & 31] = xdbl[(rbase + l8 + (t >> 5)) * 96 + 64 + (t & 31)];
    __syncthreads();
    #pragma unroll
    for (int j = 0; j < 8; j++) {
      long r = rbase + l8 + j;
      float dtv = dt[r * 2048 + d];
      float uv = bf_val(yhi[r * 2048 + d]) + bf_val(ylo[r * 2048 + d]);
      float zs = uz[r * 4096 + 2048 + d];   // already silu'ed
      float dtu = dtv * uv;
      float y = 0.f;
      #pragma unroll
      for (int s = 0; s < 4; s++) {
        float dA = expf(dtv * Av[s]);
        h[s] = fmaf(dA, h[s], dtu * BC[j][sg * 4 + s]);
        y = fmaf(h[s], BC[j][16 + sg * 4 + s], y);
      }
      y += __shfl_xor(y, 16, 64);
      y += __shfl_xor(y, 32, 64);
      if (sg == 0) {
        float ov = (y + uv * dp) * zs;
        u16 hv = bf_rne(ov);
        yhi[r * 2048 + d] = hv;
        ylo[r * 2048 + d] = bf_rne(ov - bf_val(hv));
      }
    }
  }
}

// ---------------- cross merge (accumulating per direction group) ----------------
__global__ __launch_bounds__(256) void merge_kernel(const float* __restrict__ yo,
    const float* __restrict__ gw, float* __restrict__ out, int k0, int NK) {
  int b = blockIdx.x; int c0 = blockIdx.y * 4; int t = threadIdx.x;
  int h = t >> 4, w = t & 15;
  int l0 = t;
  int l1 = (w << 4) | h;
  int l4 = (((w - h) & 15) << 4) | h;
  int l5 = (((w + h) & 15) << 4) | h;
  int lk[8] = { l0, l1, 255 - l0, 255 - l1, l4, l5, 255 - l4, 255 - l5 };
  float a0 = 0.f, a1 = 0.f, a2 = 0.f, a3 = 0.f;
  for (int kk = 0; kk < NK; kk++) {
    int k = k0 + kk;
    float g = gw[b * 8 + k];
    if (g == 0.f) continue;      // skipped stream: buffer holds poison, exact 0 contribution
    const float4 p = *(const float4*)(yo + (((long)kk * 8 + b) * 256 + lk[k]) * 1024 + c0);
    a0 = fmaf(g, p.x, a0); a1 = fmaf(g, p.y, a1); a2 = fmaf(g, p.z, a2); a3 = fmaf(g, p.w, a3);
  }
  float* op = out + ((long)b * 1024 + c0) * 256 + t;
  if (k0 == 0) { op[0] = a0; op[256] = a1; op[512] = a2; op[768] = a3; }
  else         { op[0] += a0; op[256] += a1; op[512] += a2; op[768] += a3; }
}

// ---------------- host ----------------
extern "C" void kernel_launch(void* const* d_in, const int* in_sizes, int n_in,
                              void* d_out, int out_size, void* d_ws, size_t ws_size,
                              hipStream_t stream) {
  (void)in_sizes; (void)n_in; (void)out_size;
  const float* x      = (const float*)d_in[0];
  const float* pw     = (const float*)d_in[1];
  const float* bn_g   = (const float*)d_in[2];
  const float* bn_b   = (const float*)d_in[3];
  const float* gate_w = (const float*)d_in[4];
  const float* ln_g   = (const float*)d_in[5];
  const float* ln_b   = (const float*)d_in[6];
  const float* fd_s   = (const float*)d_in[7];
  const float* in_w   = (const float*)d_in[8];
  const float* cw     = (const float*)d_in[9];
  const float* cb     = (const float*)d_in[10];
  const float* xp_w   = (const float*)d_in[11];
  const float* dtp_w  = (const float*)d_in[12];
  const float* dtp_b  = (const float*)d_in[13];
  const float* A_log  = (const float*)d_in[14];
  const float* D_p    = (const float*)d_in[15];
  const float* out_w  = (const float*)d_in[16];
  float* out = (float*)d_out;
  float* ws = (float*)d_ws;

  size_t off = 0;
  auto alloc = [&](size_t n) { float* p = ws + off; off += n; return p; };
  float* xcT    = alloc(2097152);        // (b, l, 1024)
  float* pooled = alloc((size_t)8 * 512 * 169);
  float* ysb    = alloc((size_t)8 * 128 * 169);
  float* xm     = alloc(8192);
  float* gwb    = alloc(64);
  const size_t fixed = off;

  // per-direction float counts
  const size_t PK_XGP  = 1048576;   // one xg bf16 plane (2048x1024 u16)
  const size_t PK_UZ   = 8388608;   // uz fp32 (2048x4096)
  const size_t PK_DT   = 4194304;   // dt fp32 (2048x2048)
  const size_t PK_YP   = 2097152;   // one y/u bf16 plane (2048x2048 u16)
  const size_t PK_XD   = 196608;    // x_dbl fp32 (2048x96)
  const size_t PK_YO   = 2097152;   // yo fp32 (2048x1024)
  const size_t PK_INWP = 2097152;   // one in_w bf16 plane (4096x1024 u16)
  const size_t PK_OUWP = 1048576;   // one out_w bf16 plane (1024x2048 u16)
  const size_t PK_XPWP = 131072;    // one padded xp_w bf16 plane (128x2048 u16)
  const size_t perk = 2*PK_XGP + PK_UZ + PK_DT + 2*PK_YP + PK_XD + PK_YO
                    + 2*PK_INWP + 2*PK_OUWP + 2*PK_XPWP;
  const size_t avail = ws_size / sizeof(float);
  int NK = 8;
  while (NK > 1 && fixed + perk * (size_t)NK > avail) NK >>= 1;

  u16* xghi  = (u16*)alloc(PK_XGP * NK);
  u16* xglo  = (u16*)alloc(PK_XGP * NK);
  float* uzb = alloc(PK_UZ * NK);
  float* dtb = alloc(PK_DT * NK);
  u16* yhi   = (u16*)alloc(PK_YP * NK);
  u16* ylo   = (u16*)alloc(PK_YP * NK);
  float* xdb = alloc(PK_XD * NK);
  float* yob = alloc(PK_YO * NK);
  u16* inwhi = (u16*)alloc(PK_INWP * NK);
  u16* inwlo = (u16*)alloc(PK_INWP * NK);
  u16* ouwhi = (u16*)alloc(PK_OUWP * NK);
  u16* ouwlo = (u16*)alloc(PK_OUWP * NK);
  u16* xpwhi = (u16*)alloc(PK_XPWP * NK);
  u16* xpwlo = (u16*)alloc(PK_XPWP * NK);

  // stage 1: pyramid + concat
  copyx_kernel<<<4096, 256, 0, stream>>>(x, xcT);
  pool0_kernel<<<dim3(8, 128), 256, 0, stream>>>(x, pw, bn_g, bn_b, xcT);
  const int svals[3] = {5, 9, 13};
  for (int i = 0; i < 3; i++) {
    int s = svals[i], s2 = s * s;
    int tot = 8 * 512 * s2;
    apool_kernel<<<(tot + 255) / 256, 256, 0, stream>>>(x, pooled, s);
    cbr_kernel<<<dim3(8, 128), 256, 0, stream>>>(pooled, pw + (long)(i + 1) * 128 * 512,
                                                 bn_g + (i + 1) * 128, bn_b + (i + 1) * 128,
                                                 ysb, s2);
    resize_kernel<<<dim3(8, 128), 256, 0, stream>>>(ysb, xcT, s, 128 * (i + 1));
  }
  xcmean_kernel<<<32, 256, 0, stream>>>(xcT, xm);
  gate_kernel<<<1, 64, 0, stream>>>(xm, gate_w, gwb);

  // stage 2: per-direction groups
  for (int k0 = 0; k0 < 8; k0 += NK) {
    // split this group's weights into bf16 hi/lo planes
    {
      long n4 = (long)NK * 4096 * 1024 / 4;
      split_kernel<<<(int)((n4 + 255) / 256), 256, 0, stream>>>(
          in_w + (long)k0 * 4096 * 1024, inwhi, inwlo, n4);
      long m4 = (long)NK * 1024 * 2048 / 4;
      split_kernel<<<(int)((m4 + 255) / 256), 256, 0, stream>>>(
          out_w + (long)k0 * 1024 * 2048, ouwhi, ouwlo, m4);
      long p4 = (long)NK * 128 * 2048 / 4;
      xpw_split_kernel<<<(int)((p4 + 255) / 256), 256, 0, stream>>>(
          xp_w, xpwhi, xpwlo, k0, NK);
    }
    fd_gate_kernel<<<dim3(256, NK * 8), 256, 0, stream>>>(xcT, ln_g, ln_b, fd_s,
                                                          xghi, xglo, k0, gwb);
    // uz = xg @ in_w[k].T  (N=4096; silu applied to z half)
    gemm_x3<1><<<dim3(16, 32, NK), 256, 0, stream>>>(
        xghi, xglo, (long)2 * PK_XGP,
        inwhi, inwlo, (long)2 * PK_INWP,
        uzb, (long)PK_UZ, 1024, 4096, 4096, k0, gwb);
    // depthwise conv + silu, chunked over L -> split-bf16 u into y planes
    conv_split_kernel<<<NK * 512, 256, 0, stream>>>(uzb, cw, cb, yhi, ylo, k0, gwb);
    // x_dbl = u @ xp_w[k].T  (N=96, padded to 128)
    gemm_x3<0><<<dim3(16, 1, NK), 256, 0, stream>>>(
        yhi, ylo, (long)2 * PK_YP,
        xpwhi, xpwlo, (long)2 * PK_XPWP,
        xdb, (long)PK_XD, 2048, 96, 96, k0, gwb);
    // dt = softplus(x_dbl[:, :64] @ dtp_w[k].T + dtp_b[k])  (N=64 -> 1 n-block)
    gemm_nt<1><<<dim3(16, 1, NK), 256, 0, stream>>>(
        xdb, 96, (long)PK_XD, dtp_w + (long)k0 * 2048 * 64, (long)2048 * 64,
        dtb, 2048, (long)PK_DT, 2048, 64, dtp_b + (long)k0 * 2048, 2048, k0, gwb);
    // selective scan + (y + u*Dp)*silu(z) -> split-bf16 y planes (in-place over u)
    scan_kernel<<<dim3(32, NK * 8), 256, 0, stream>>>(dtb, uzb, xdb, A_log, D_p,
                                                      yhi, ylo, k0, gwb);
    // y_out = y @ out_w[k].T  (N=1024)
    gemm_x3<0><<<dim3(16, 8, NK), 256, 0, stream>>>(
        yhi, ylo, (long)2 * PK_YP,
        ouwhi, ouwlo, (long)2 * PK_OUWP,
        yob, (long)PK_YO, 2048, 1024, 1024, k0, gwb);
    // cross-merge accumulate into d_out
    merge_kernel<<<dim3(8, 256), 256, 0, stream>>>(yob, gwb, out, k0, NK);
  }
}